// Round 1
// baseline (1792.509 us; speedup 1.0000x reference)
//
#include <hip/hip_runtime.h>
#include <hip/hip_bf16.h>

#define DIM 128

static inline int cdiv(int a, int b) { return (a + b - 1) / b; }
static inline size_t align256(size_t x) { return (x + 255) & ~size_t(255); }

// -------- kernel 1: segment offsets via binary search (seg sorted ascending)
__global__ void seg_offsets_kernel(const int* __restrict__ seg, int m, int nseg,
                                   int* __restrict__ off) {
    int s = blockIdx.x * blockDim.x + threadIdx.x;
    if (s > nseg) return;
    // lower_bound: first i with seg[i] >= s
    int lo = 0, hi = m;
    while (lo < hi) {
        int mid = (lo + hi) >> 1;
        if (seg[mid] < s) lo = mid + 1; else hi = mid;
    }
    off[s] = lo;
}

// -------- kernel 2: gather + segment mean. One 128-thread block per segment.
__global__ __launch_bounds__(DIM)
void seg_mean_gather_kernel(const float* __restrict__ src, const int* __restrict__ map,
                            const int* __restrict__ off, float* __restrict__ dst,
                            int nseg) {
    int s = blockIdx.x;
    if (s >= nseg) return;
    int d = threadIdx.x;
    int beg = off[s], end = off[s + 1];
    float acc = 0.f;
    for (int j = beg; j < end; ++j) {
        int r = map[j];                      // block-uniform -> scalar load
        acc += src[(size_t)r * DIM + d];     // coalesced 512B row read
    }
    float cnt = (float)(end - beg);
    dst[(size_t)s * DIM + d] = acc / fmaxf(cnt, 1.0f);
}

// -------- kernel 3: fused y = relu(layernorm(x @ W + b) * g + be), in-place safe.
// 128 threads; thread d owns output column d; W column kept in 128 VGPRs.
template <int ROWS>
__global__ __launch_bounds__(DIM)
void linear_ln_relu_kernel(const float* __restrict__ X, float* __restrict__ Y,
                           const float* __restrict__ W, const float* __restrict__ b,
                           const float* __restrict__ g, const float* __restrict__ be,
                           int nrows) {
    int d = threadIdx.x;
    int row0 = blockIdx.x * ROWS;
    if (row0 >= nrows) return;

    // Load W column d into registers (coalesced across threads per k).
    float w[DIM];
#pragma unroll
    for (int k = 0; k < DIM; ++k) w[k] = W[k * DIM + d];
    float bias = b[d], gg = g[d], bb = be[d];

    __shared__ float xs[DIM];
    __shared__ float p1[2], p2[2];
    int wid = d >> 6;

    int rend = min(row0 + ROWS, nrows);
    for (int r = row0; r < rend; ++r) {
        __syncthreads();                       // protect xs & p from prev iter readers
        xs[d] = X[(size_t)r * DIM + d];
        __syncthreads();

        float acc = bias;
#pragma unroll
        for (int k = 0; k < DIM; ++k) acc += xs[k] * w[k];   // xs[k] = LDS broadcast

        // layernorm over the 128 outputs of this row (2 waves)
        float s1 = acc, s2 = acc * acc;
#pragma unroll
        for (int o = 1; o < 64; o <<= 1) {
            s1 += __shfl_xor(s1, o);
            s2 += __shfl_xor(s2, o);
        }
        if ((d & 63) == 0) { p1[wid] = s1; p2[wid] = s2; }
        __syncthreads();
        float S1 = p1[0] + p1[1];
        float S2 = p2[0] + p2[1];
        float m = S1 * (1.0f / DIM);
        float v = S2 * (1.0f / DIM) - m * m;
        float y = (acc - m) * rsqrtf(v + 1e-5f) * gg + bb;
        Y[(size_t)r * DIM + d] = fmaxf(y, 0.0f);
    }
}

// -------- kernel 4: classifier (128 x NCLS) + log_softmax. One wave per row.
__global__ __launch_bounds__(256)
void classifier_logsoftmax_kernel(const float* __restrict__ X, const float* __restrict__ Wc,
                                  const float* __restrict__ bc, float* __restrict__ out,
                                  int nrows, int ncls) {
    int wid = threadIdx.x >> 6;
    int lane = threadIdx.x & 63;
    int r = blockIdx.x * 4 + wid;
    if (r >= nrows) return;

    float x0 = X[(size_t)r * DIM + lane];
    float x1 = X[(size_t)r * DIM + 64 + lane];

    float yv[16];
#pragma unroll 10
    for (int c = 0; c < ncls; ++c) {
        float p = x0 * Wc[lane * ncls + c] + x1 * Wc[(64 + lane) * ncls + c];
#pragma unroll
        for (int o = 1; o < 64; o <<= 1) p += __shfl_xor(p, o);
        yv[c] = p + bc[c];
    }
    float mx = yv[0];
#pragma unroll 10
    for (int c = 1; c < ncls; ++c) mx = fmaxf(mx, yv[c]);
    float se = 0.f;
#pragma unroll 10
    for (int c = 0; c < ncls; ++c) se += expf(yv[c] - mx);
    float lse = mx + logf(se);
    if (lane == 0) {
#pragma unroll 10
        for (int c = 0; c < ncls; ++c) out[(size_t)r * ncls + c] = yv[c] - lse;
    }
}

extern "C" void kernel_launch(void* const* d_in, const int* in_sizes, int n_in,
                              void* d_out, int out_size, void* d_ws, size_t ws_size,
                              hipStream_t stream) {
    const float* node_x   = (const float*)d_in[0];
    const int*   nodes_map= (const int*)d_in[1];
    const int*   edge_seg = (const int*)d_in[2];
    const int*   edges_map= (const int*)d_in[3];
    const int*   node_seg = (const int*)d_in[4];
    // d_in[5] = num_edges (device scalar); value fixed by problem definition.
    const float* W_e = (const float*)d_in[6];
    const float* b_e = (const float*)d_in[7];
    const float* g_e = (const float*)d_in[8];
    const float* be_e= (const float*)d_in[9];
    const float* W_n = (const float*)d_in[10];
    const float* b_n = (const float*)d_in[11];
    const float* g_n = (const float*)d_in[12];
    const float* be_n= (const float*)d_in[13];
    const float* W_c = (const float*)d_in[14];
    const float* b_c = (const float*)d_in[15];
    float* out = (float*)d_out;

    const int N = in_sizes[0] / DIM;           // 100000
    const int M = in_sizes[1];                 // 800000
    const int E = 200000;                      // N_EDGES (problem constant)
    const int L = in_sizes[6] / (DIM * DIM);   // 2
    const int C = in_sizes[15];                // 10

    // workspace carve-up
    char* ws = (char*)d_ws;
    int* edge_off = (int*)ws;  ws += align256((size_t)(E + 1) * sizeof(int));
    int* node_off = (int*)ws;  ws += align256((size_t)(N + 1) * sizeof(int));
    float* exb    = (float*)ws; ws += align256((size_t)E * DIM * sizeof(float));
    float* xb     = (float*)ws; ws += align256((size_t)N * DIM * sizeof(float));
    (void)ws_size;

    seg_offsets_kernel<<<cdiv(E + 1, 256), 256, 0, stream>>>(edge_seg, M, E, edge_off);
    seg_offsets_kernel<<<cdiv(N + 1, 256), 256, 0, stream>>>(node_seg, M, N, node_off);

    constexpr int ROWS = 64;
    const float* xcur = node_x;
    for (int i = 0; i < L; ++i) {
        // N2E: gather node feats, mean per hyperedge
        seg_mean_gather_kernel<<<E, DIM, 0, stream>>>(xcur, nodes_map, edge_off, exb, E);
        linear_ln_relu_kernel<ROWS><<<cdiv(E, ROWS), DIM, 0, stream>>>(
            exb, exb, W_e + (size_t)i * DIM * DIM, b_e + i * DIM, g_e + i * DIM,
            be_e + i * DIM, E);
        // E2N: gather edge feats, mean per node
        seg_mean_gather_kernel<<<N, DIM, 0, stream>>>(exb, edges_map, node_off, xb, N);
        linear_ln_relu_kernel<ROWS><<<cdiv(N, ROWS), DIM, 0, stream>>>(
            xb, xb, W_n + (size_t)i * DIM * DIM, b_n + i * DIM, g_n + i * DIM,
            be_n + i * DIM, N);
        xcur = xb;
    }

    classifier_logsoftmax_kernel<<<cdiv(N, 4), 256, 0, stream>>>(xcur, W_c, b_c, out, N, C);
}

// Round 2
// 711.843 us; speedup vs baseline: 2.5181x; 2.5181x over previous
//
#include <hip/hip_runtime.h>
#include <hip/hip_bf16.h>

#define DIM 128

typedef __bf16 bf16x8 __attribute__((ext_vector_type(8)));
typedef float f32x4 __attribute__((ext_vector_type(4)));

static inline int cdiv(int a, int b) { return (a + b - 1) / b; }
static inline size_t align256(size_t x) { return (x + 255) & ~size_t(255); }

__device__ inline unsigned short f2bf(float f) {
    union { float f; unsigned int u; } v; v.f = f;
    unsigned int r = v.u + 0x7fff + ((v.u >> 16) & 1);   // RNE
    return (unsigned short)(r >> 16);
}
__device__ inline float bf2f(unsigned short h) {
    union { unsigned int u; float f; } v; v.u = ((unsigned int)h) << 16;
    return v.f;
}

// -------- kernel 1: segment offsets via binary search (seg sorted ascending)
__global__ void seg_offsets_kernel(const int* __restrict__ seg, int m, int nseg,
                                   int* __restrict__ off) {
    int s = blockIdx.x * blockDim.x + threadIdx.x;
    if (s > nseg) return;
    int lo = 0, hi = m;
    while (lo < hi) {
        int mid = (lo + hi) >> 1;
        if (seg[mid] < s) lo = mid + 1; else hi = mid;
    }
    off[s] = lo;
}

// -------- kernel 2: fp32 -> bf16 convert (node_x), float4 granularity
__global__ void f32_to_bf16_kernel(const float* __restrict__ in,
                                   unsigned short* __restrict__ out, int n4) {
    int i = blockIdx.x * blockDim.x + threadIdx.x;
    if (i >= n4) return;
    float4 v = ((const float4*)in)[i];
    ushort4 o;
    o.x = f2bf(v.x); o.y = f2bf(v.y); o.z = f2bf(v.z); o.w = f2bf(v.w);
    ((ushort4*)out)[i] = o;
}

// -------- kernel 3: pre-swizzle W (4 matrices of 128x128 fp32) into frag-major bf16.
// Entry e=(t,n,lane): 8 bf16 = W[t*32 + (lane>>4)*8 + j][n*16 + (lane&15)], j=0..7.
__global__ void swizzle_w_kernel(const float* __restrict__ W_e, const float* __restrict__ W_n,
                                 unsigned short* __restrict__ wsw) {
    int gid = blockIdx.x * blockDim.x + threadIdx.x;  // 4 * 2048 threads
    int mi = gid >> 11;
    int e = gid & 2047;
    const float* W = (mi < 2) ? (W_e + (size_t)mi * DIM * DIM)
                              : (W_n + (size_t)(mi - 2) * DIM * DIM);
    int t = e >> 9, n = (e >> 6) & 7, lane = e & 63;
    int q = lane >> 4, c = lane & 15;
    int k0 = t * 32 + q * 8, col = n * 16 + c;
    unsigned short vals[8];
#pragma unroll
    for (int j = 0; j < 8; ++j) vals[j] = f2bf(W[(size_t)(k0 + j) * DIM + col]);
    ushort4* dst = (ushort4*)(wsw + (size_t)gid * 8);
    dst[0] = make_ushort4(vals[0], vals[1], vals[2], vals[3]);
    dst[1] = make_ushort4(vals[4], vals[5], vals[6], vals[7]);
}

// -------- kernel 4: gather + segment mean on bf16 rows. One wave per segment.
__global__ __launch_bounds__(256)
void seg_mean_bf16_kernel(const unsigned int* __restrict__ src32, const int* __restrict__ map,
                          const int* __restrict__ off, unsigned int* __restrict__ dst32,
                          int nseg) {
    int w = threadIdx.x >> 6, lane = threadIdx.x & 63;
    int s = blockIdx.x * 4 + w;
    if (s >= nseg) return;
    int beg = off[s], end = off[s + 1];
    float a0 = 0.f, a1 = 0.f;
    for (int j = beg; j < end; ++j) {
        int r = map[j];
        unsigned int v = src32[(size_t)r * 64 + lane];   // 2 bf16, coalesced 256B/wave
        a0 += bf2f((unsigned short)(v & 0xffffu));
        a1 += bf2f((unsigned short)(v >> 16));
    }
    float inv = 1.f / fmaxf((float)(end - beg), 1.f);
    unsigned int o = (unsigned int)f2bf(a0 * inv) | ((unsigned int)f2bf(a1 * inv) << 16);
    dst32[(size_t)s * 64 + lane] = o;
}

// -------- kernel 5: Y = relu(LN(X @ W + b) * g + be), bf16 in/out, MFMA 16x16x32.
// 4 waves/block; wave handles OT*RT*16 = 64 rows; block = 256 rows. In-place safe.
#define GEMM_OT 2
#define GEMM_RT 2
#define ROWS_PER_BLOCK 256

__global__ __launch_bounds__(256)
void gemm_ln_relu_kernel(const unsigned short* __restrict__ X, unsigned short* __restrict__ Y,
                         const unsigned short* __restrict__ Wsw, const float* __restrict__ b,
                         const float* __restrict__ g, const float* __restrict__ be,
                         int nrows) {
    __shared__ bf16x8 wlds[2048];   // 32 KB, frag-major: [(t*8+n)*64 + lane]
    int tid = threadIdx.x;
    int w = tid >> 6, lane = tid & 63;
    int q = lane >> 4, c = lane & 15;

    {   // stage swizzled W (global layout == LDS layout)
        const uint4* gsrc = (const uint4*)Wsw;
        uint4* ldst = (uint4*)wlds;
#pragma unroll
        for (int i = 0; i < 8; ++i) ldst[tid + i * 256] = gsrc[tid + i * 256];
    }
    __syncthreads();

    float bcol[8], gcol[8], becol[8];
#pragma unroll
    for (int n = 0; n < 8; ++n) {
        int col = n * 16 + c;
        bcol[n] = b[col]; gcol[n] = g[col]; becol[n] = be[col];
    }

    long base = (long)blockIdx.x * ROWS_PER_BLOCK + w * (GEMM_OT * GEMM_RT * 16);

    for (int ot = 0; ot < GEMM_OT; ++ot) {
        long tbase = base + ot * (GEMM_RT * 16);

        bf16x8 a[GEMM_RT][4];
#pragma unroll
        for (int rt = 0; rt < GEMM_RT; ++rt) {
            long rowA = tbase + rt * 16 + c;
            if (rowA > nrows - 1) rowA = nrows - 1;
            const bf16x8* ap = (const bf16x8*)(X + rowA * DIM + q * 8);
#pragma unroll
            for (int t = 0; t < 4; ++t) a[rt][t] = ap[t * 4];   // k-offset t*32 elems
        }

        f32x4 acc[GEMM_RT][8];
#pragma unroll
        for (int rt = 0; rt < GEMM_RT; ++rt)
#pragma unroll
            for (int n = 0; n < 8; ++n) acc[rt][n] = f32x4{0.f, 0.f, 0.f, 0.f};

#pragma unroll
        for (int n = 0; n < 8; ++n)
#pragma unroll
            for (int t = 0; t < 4; ++t) {
                bf16x8 bf = wlds[(t * 8 + n) * 64 + lane];
#pragma unroll
                for (int rt = 0; rt < GEMM_RT; ++rt)
                    acc[rt][n] = __builtin_amdgcn_mfma_f32_16x16x32_bf16(
                        a[rt][t], bf, acc[rt][n], 0, 0, 0);
            }

#pragma unroll
        for (int rt = 0; rt < GEMM_RT; ++rt) {
#pragma unroll
            for (int n = 0; n < 8; ++n)
#pragma unroll
                for (int j = 0; j < 4; ++j) acc[rt][n][j] += bcol[n];

            // per-row mean/var; lane's 4 rows = tbase + rt*16 + q*4 + j
            float s1[4], s2[4];
#pragma unroll
            for (int j = 0; j < 4; ++j) {
                float t1 = 0.f, t2 = 0.f;
#pragma unroll
                for (int n = 0; n < 8; ++n) { float v = acc[rt][n][j]; t1 += v; t2 += v * v; }
                s1[j] = t1; s2[j] = t2;
            }
#pragma unroll
            for (int o = 1; o < 16; o <<= 1)
#pragma unroll
                for (int j = 0; j < 4; ++j) {
                    s1[j] += __shfl_xor(s1[j], o);
                    s2[j] += __shfl_xor(s2[j], o);
                }
#pragma unroll
            for (int j = 0; j < 4; ++j) {
                long row = tbase + rt * 16 + q * 4 + j;
                if (row >= nrows) continue;
                float m = s1[j] * (1.f / DIM);
                float v = s2[j] * (1.f / DIM) - m * m;
                float inv = rsqrtf(v + 1e-5f);
#pragma unroll
                for (int n = 0; n < 8; ++n) {
                    float y = (acc[rt][n][j] - m) * inv * gcol[n] + becol[n];
                    Y[row * DIM + n * 16 + c] = f2bf(fmaxf(y, 0.f));
                }
            }
        }
    }
}

// -------- kernel 6: classifier (128 x NCLS) + log_softmax, bf16 input. One wave/row.
__global__ __launch_bounds__(256)
void classifier_logsoftmax_kernel(const unsigned short* __restrict__ X,
                                  const float* __restrict__ Wc, const float* __restrict__ bc,
                                  float* __restrict__ out, int nrows, int ncls) {
    int wid = threadIdx.x >> 6;
    int lane = threadIdx.x & 63;
    int r = blockIdx.x * 4 + wid;
    if (r >= nrows) return;

    float x0 = bf2f(X[(size_t)r * DIM + lane]);
    float x1 = bf2f(X[(size_t)r * DIM + 64 + lane]);

    float yv[16];
#pragma unroll 10
    for (int c = 0; c < ncls; ++c) {
        float p = x0 * Wc[lane * ncls + c] + x1 * Wc[(64 + lane) * ncls + c];
#pragma unroll
        for (int o = 1; o < 64; o <<= 1) p += __shfl_xor(p, o);
        yv[c] = p + bc[c];
    }
    float mx = yv[0];
#pragma unroll 10
    for (int c = 1; c < ncls; ++c) mx = fmaxf(mx, yv[c]);
    float se = 0.f;
#pragma unroll 10
    for (int c = 0; c < ncls; ++c) se += expf(yv[c] - mx);
    float lse = mx + logf(se);
    if (lane == 0) {
#pragma unroll 10
        for (int c = 0; c < ncls; ++c) out[(size_t)r * ncls + c] = yv[c] - lse;
    }
}

extern "C" void kernel_launch(void* const* d_in, const int* in_sizes, int n_in,
                              void* d_out, int out_size, void* d_ws, size_t ws_size,
                              hipStream_t stream) {
    const float* node_x    = (const float*)d_in[0];
    const int*   nodes_map = (const int*)d_in[1];
    const int*   edge_seg  = (const int*)d_in[2];
    const int*   edges_map = (const int*)d_in[3];
    const int*   node_seg  = (const int*)d_in[4];
    const float* W_e = (const float*)d_in[6];
    const float* b_e = (const float*)d_in[7];
    const float* g_e = (const float*)d_in[8];
    const float* be_e= (const float*)d_in[9];
    const float* W_n = (const float*)d_in[10];
    const float* b_n = (const float*)d_in[11];
    const float* g_n = (const float*)d_in[12];
    const float* be_n= (const float*)d_in[13];
    const float* W_c = (const float*)d_in[14];
    const float* b_c = (const float*)d_in[15];
    float* out = (float*)d_out;

    const int N = in_sizes[0] / DIM;           // 100000
    const int M = in_sizes[1];                 // 800000
    const int E = 200000;                      // N_EDGES (problem constant)
    const int L = in_sizes[6] / (DIM * DIM);   // 2
    const int C = in_sizes[15];                // 10

    // workspace carve-up
    char* ws = (char*)d_ws;
    int* edge_off = (int*)ws;           ws += align256((size_t)(E + 1) * sizeof(int));
    int* node_off = (int*)ws;           ws += align256((size_t)(N + 1) * sizeof(int));
    unsigned short* wsw = (unsigned short*)ws;      ws += align256((size_t)4 * 2048 * 8 * sizeof(unsigned short));
    unsigned short* node_xb = (unsigned short*)ws;  ws += align256((size_t)N * DIM * sizeof(unsigned short));
    unsigned short* exb = (unsigned short*)ws;      ws += align256((size_t)E * DIM * sizeof(unsigned short));
    unsigned short* xb  = (unsigned short*)ws;      ws += align256((size_t)N * DIM * sizeof(unsigned short));
    (void)ws_size;

    seg_offsets_kernel<<<cdiv(E + 1, 256), 256, 0, stream>>>(edge_seg, M, E, edge_off);
    seg_offsets_kernel<<<cdiv(N + 1, 256), 256, 0, stream>>>(node_seg, M, N, node_off);
    f32_to_bf16_kernel<<<cdiv(N * DIM / 4, 256), 256, 0, stream>>>(node_x, node_xb, N * DIM / 4);
    swizzle_w_kernel<<<32, 256, 0, stream>>>(W_e, W_n, wsw);

    const unsigned short* xcur = node_xb;
    for (int i = 0; i < L; ++i) {
        seg_mean_bf16_kernel<<<cdiv(E, 4), 256, 0, stream>>>(
            (const unsigned int*)xcur, nodes_map, edge_off, (unsigned int*)exb, E);
        gemm_ln_relu_kernel<<<cdiv(E, ROWS_PER_BLOCK), 256, 0, stream>>>(
            exb, exb, wsw + (size_t)i * 16384, b_e + i * DIM, g_e + i * DIM, be_e + i * DIM, E);
        seg_mean_bf16_kernel<<<cdiv(N, 4), 256, 0, stream>>>(
            (const unsigned int*)exb, edges_map, node_off, (unsigned int*)xb, N);
        gemm_ln_relu_kernel<<<cdiv(N, ROWS_PER_BLOCK), 256, 0, stream>>>(
            xb, xb, wsw + (size_t)(2 + i) * 16384, b_n + i * DIM, g_n + i * DIM, be_n + i * DIM, N);
        xcur = xb;
    }

    classifier_logsoftmax_kernel<<<cdiv(N, 4), 256, 0, stream>>>(xcur, W_c, b_c, out, N, C);
}

// Round 4
// 636.438 us; speedup vs baseline: 2.8165x; 1.1185x over previous
//
#include <hip/hip_runtime.h>
#include <hip/hip_bf16.h>

#define DIM 128

typedef __bf16 bf16x8 __attribute__((ext_vector_type(8)));
typedef float f32x4 __attribute__((ext_vector_type(4)));

static inline int cdiv(int a, int b) { return (a + b - 1) / b; }
static inline size_t align256(size_t x) { return (x + 255) & ~size_t(255); }

__device__ inline unsigned short f2bf(float f) {
    union { float f; unsigned int u; } v; v.f = f;
    unsigned int r = v.u + 0x7fff + ((v.u >> 16) & 1);   // RNE
    return (unsigned short)(r >> 16);
}
__device__ inline float bf2f(unsigned short h) {
    union { unsigned int u; float f; } v; v.u = ((unsigned int)h) << 16;
    return v.f;
}

// -------- kernel 1: segment offsets via binary search (seg sorted ascending)
__global__ void seg_offsets_kernel(const int* __restrict__ seg, int m, int nseg,
                                   int* __restrict__ off) {
    int s = blockIdx.x * blockDim.x + threadIdx.x;
    if (s > nseg) return;
    int lo = 0, hi = m;
    while (lo < hi) {
        int mid = (lo + hi) >> 1;
        if (seg[mid] < s) lo = mid + 1; else hi = mid;
    }
    off[s] = lo;
}

// -------- kernel 2: fp32 -> bf16 convert (node_x), float4 granularity
__global__ void f32_to_bf16_kernel(const float* __restrict__ in,
                                   unsigned short* __restrict__ out, int n4) {
    int i = blockIdx.x * blockDim.x + threadIdx.x;
    if (i >= n4) return;
    float4 v = ((const float4*)in)[i];
    ushort4 o;
    o.x = f2bf(v.x); o.y = f2bf(v.y); o.z = f2bf(v.z); o.w = f2bf(v.w);
    ((ushort4*)out)[i] = o;
}

// -------- kernel 3: pre-swizzle W (4 matrices of 128x128 fp32) into frag-major bf16.
// Entry e=(t,n,lane): 8 bf16 = W[t*32 + (lane>>4)*8 + j][n*16 + (lane&15)], j=0..7.
__global__ void swizzle_w_kernel(const float* __restrict__ W_e, const float* __restrict__ W_n,
                                 unsigned short* __restrict__ wsw) {
    int gid = blockIdx.x * blockDim.x + threadIdx.x;  // 4 * 2048 threads
    int mi = gid >> 11;
    int e = gid & 2047;
    const float* W = (mi < 2) ? (W_e + (size_t)mi * DIM * DIM)
                              : (W_n + (size_t)(mi - 2) * DIM * DIM);
    int t = e >> 9, n = (e >> 6) & 7, lane = e & 63;
    int q = lane >> 4, c = lane & 15;
    int k0 = t * 32 + q * 8, col = n * 16 + c;
    unsigned short vals[8];
#pragma unroll
    for (int j = 0; j < 8; ++j) vals[j] = f2bf(W[(size_t)(k0 + j) * DIM + col]);
    ushort4* dst = (ushort4*)(wsw + (size_t)gid * 8);
    dst[0] = make_ushort4(vals[0], vals[1], vals[2], vals[3]);
    dst[1] = make_ushort4(vals[4], vals[5], vals[6], vals[7]);
}

// -------- kernel 4: gather + segment mean on bf16 rows. One wave per segment.
__global__ __launch_bounds__(256)
void seg_mean_bf16_kernel(const unsigned int* __restrict__ src32, const int* __restrict__ map,
                          const int* __restrict__ off, unsigned int* __restrict__ dst32,
                          int nseg) {
    int w = threadIdx.x >> 6, lane = threadIdx.x & 63;
    int s = blockIdx.x * 4 + w;
    if (s >= nseg) return;
    int beg = off[s], end = off[s + 1];
    float a0 = 0.f, a1 = 0.f;
    for (int j = beg; j < end; ++j) {
        int r = map[j];
        unsigned int v = src32[(size_t)r * 64 + lane];   // 2 bf16, coalesced 256B/wave
        a0 += bf2f((unsigned short)(v & 0xffffu));
        a1 += bf2f((unsigned short)(v >> 16));
    }
    float inv = 1.f / fmaxf((float)(end - beg), 1.f);
    unsigned int o = (unsigned int)f2bf(a0 * inv) | ((unsigned int)f2bf(a1 * inv) << 16);
    dst32[(size_t)s * 64 + lane] = o;
}

// -------- kernel 5: Y = relu(LN(X @ W + b) * g + be), bf16 in/out, MFMA 16x16x32.
// 4 waves/block; wave handles OT*RT*16 = 64 rows; block = 256 rows. In-place safe.
#define GEMM_OT 2
#define GEMM_RT 2
#define ROWS_PER_BLOCK 256

__global__ __launch_bounds__(256)
void gemm_ln_relu_kernel(const unsigned short* __restrict__ X, unsigned short* __restrict__ Y,
                         const unsigned short* __restrict__ Wsw, const float* __restrict__ b,
                         const float* __restrict__ g, const float* __restrict__ be,
                         int nrows) {
    __shared__ bf16x8 wlds[2048];   // 32 KB, frag-major: [(t*8+n)*64 + lane]
    int tid = threadIdx.x;
    int w = tid >> 6, lane = tid & 63;
    int q = lane >> 4, c = lane & 15;

    {   // stage swizzled W (global layout == LDS layout)
        const uint4* gsrc = (const uint4*)Wsw;
        uint4* ldst = (uint4*)wlds;
#pragma unroll
        for (int i = 0; i < 8; ++i) ldst[tid + i * 256] = gsrc[tid + i * 256];
    }
    __syncthreads();

    float bcol[8], gcol[8], becol[8];
#pragma unroll
    for (int n = 0; n < 8; ++n) {
        int col = n * 16 + c;
        bcol[n] = b[col]; gcol[n] = g[col]; becol[n] = be[col];
    }

    long base = (long)blockIdx.x * ROWS_PER_BLOCK + w * (GEMM_OT * GEMM_RT * 16);

    for (int ot = 0; ot < GEMM_OT; ++ot) {
        long tbase = base + ot * (GEMM_RT * 16);

        bf16x8 a[GEMM_RT][4];
#pragma unroll
        for (int rt = 0; rt < GEMM_RT; ++rt) {
            long rowA = tbase + rt * 16 + c;
            if (rowA > nrows - 1) rowA = nrows - 1;
            const bf16x8* ap = (const bf16x8*)(X + rowA * DIM + q * 8);
#pragma unroll
            for (int t = 0; t < 4; ++t) a[rt][t] = ap[t * 4];   // k-offset t*32 elems
        }

        f32x4 acc[GEMM_RT][8];
#pragma unroll
        for (int rt = 0; rt < GEMM_RT; ++rt)
#pragma unroll
            for (int n = 0; n < 8; ++n) acc[rt][n] = f32x4{0.f, 0.f, 0.f, 0.f};

#pragma unroll
        for (int n = 0; n < 8; ++n)
#pragma unroll
            for (int t = 0; t < 4; ++t) {
                bf16x8 bf = wlds[(t * 8 + n) * 64 + lane];
#pragma unroll
                for (int rt = 0; rt < GEMM_RT; ++rt)
                    acc[rt][n] = __builtin_amdgcn_mfma_f32_16x16x32_bf16(
                        a[rt][t], bf, acc[rt][n], 0, 0, 0);
            }

#pragma unroll
        for (int rt = 0; rt < GEMM_RT; ++rt) {
#pragma unroll
            for (int n = 0; n < 8; ++n)
#pragma unroll
                for (int j = 0; j < 4; ++j) acc[rt][n][j] += bcol[n];

            // per-row mean/var; lane's 4 rows = tbase + rt*16 + q*4 + j
            float s1[4], s2[4];
#pragma unroll
            for (int j = 0; j < 4; ++j) {
                float t1 = 0.f, t2 = 0.f;
#pragma unroll
                for (int n = 0; n < 8; ++n) { float v = acc[rt][n][j]; t1 += v; t2 += v * v; }
                s1[j] = t1; s2[j] = t2;
            }
#pragma unroll
            for (int o = 1; o < 16; o <<= 1)
#pragma unroll
                for (int j = 0; j < 4; ++j) {
                    s1[j] += __shfl_xor(s1[j], o);
                    s2[j] += __shfl_xor(s2[j], o);
                }
#pragma unroll
            for (int j = 0; j < 4; ++j) {
                long row = tbase + rt * 16 + q * 4 + j;
                if (row >= nrows) continue;
                float m = s1[j] * (1.f / DIM);
                float v = s2[j] * (1.f / DIM) - m * m;
                float inv = rsqrtf(v + 1e-5f);
#pragma unroll
                for (int n = 0; n < 8; ++n) {
                    float y = (acc[rt][n][j] - m) * inv * gcol[n] + becol[n];
                    Y[row * DIM + n * 16 + c] = f2bf(fmaxf(y, 0.f));
                }
            }
        }
    }
}

// -------- kernel 6: classifier + log_softmax, thread-per-row.
// Row = 256 B = 16 uint4 loads (NOT 8 — that was the R3 bug).
__global__ __launch_bounds__(256)
void classifier_logsoftmax_v2_kernel(const unsigned short* __restrict__ X,
                                     const float* __restrict__ Wc,
                                     const float* __restrict__ bc,
                                     float* __restrict__ out, int nrows) {
    int r = blockIdx.x * 256 + threadIdx.x;
    if (r >= nrows) return;

    uint4 rowv[16];
    const uint4* xp = (const uint4*)(X + (size_t)r * DIM);
#pragma unroll
    for (int i = 0; i < 16; ++i) rowv[i] = xp[i];
    const unsigned int* ru = (const unsigned int*)rowv;

    float acc[10];
#pragma unroll
    for (int c = 0; c < 10; ++c) acc[c] = bc[c];

#pragma unroll 8
    for (int j = 0; j < 64; ++j) {
        unsigned int u = ru[j];
        float x0 = bf2f((unsigned short)(u & 0xffffu));
        float x1 = bf2f((unsigned short)(u >> 16));
#pragma unroll
        for (int c = 0; c < 10; ++c)
            acc[c] += x0 * Wc[(2 * j) * 10 + c] + x1 * Wc[(2 * j + 1) * 10 + c];
    }

    float mx = acc[0];
#pragma unroll
    for (int c = 1; c < 10; ++c) mx = fmaxf(mx, acc[c]);
    float se = 0.f;
#pragma unroll
    for (int c = 0; c < 10; ++c) se += expf(acc[c] - mx);
    float lse = mx + logf(se);
    float* op = out + (size_t)r * 10;
#pragma unroll
    for (int c = 0; c < 10; ++c) op[c] = acc[c] - lse;
}

extern "C" void kernel_launch(void* const* d_in, const int* in_sizes, int n_in,
                              void* d_out, int out_size, void* d_ws, size_t ws_size,
                              hipStream_t stream) {
    const float* node_x    = (const float*)d_in[0];
    const int*   nodes_map = (const int*)d_in[1];
    const int*   edge_seg  = (const int*)d_in[2];
    const int*   edges_map = (const int*)d_in[3];
    const int*   node_seg  = (const int*)d_in[4];
    const float* W_e = (const float*)d_in[6];
    const float* b_e = (const float*)d_in[7];
    const float* g_e = (const float*)d_in[8];
    const float* be_e= (const float*)d_in[9];
    const float* W_n = (const float*)d_in[10];
    const float* b_n = (const float*)d_in[11];
    const float* g_n = (const float*)d_in[12];
    const float* be_n= (const float*)d_in[13];
    const float* W_c = (const float*)d_in[14];
    const float* b_c = (const float*)d_in[15];
    float* out = (float*)d_out;

    const int N = in_sizes[0] / DIM;           // 100000
    const int M = in_sizes[1];                 // 800000
    const int E = 200000;                      // N_EDGES (problem constant)
    const int L = in_sizes[6] / (DIM * DIM);   // 2

    // workspace carve-up
    char* ws = (char*)d_ws;
    int* edge_off = (int*)ws;           ws += align256((size_t)(E + 1) * sizeof(int));
    int* node_off = (int*)ws;           ws += align256((size_t)(N + 1) * sizeof(int));
    unsigned short* wsw = (unsigned short*)ws;      ws += align256((size_t)4 * 2048 * 8 * sizeof(unsigned short));
    unsigned short* node_xb = (unsigned short*)ws;  ws += align256((size_t)N * DIM * sizeof(unsigned short));
    unsigned short* exb = (unsigned short*)ws;      ws += align256((size_t)E * DIM * sizeof(unsigned short));
    unsigned short* xb  = (unsigned short*)ws;      ws += align256((size_t)N * DIM * sizeof(unsigned short));
    (void)ws_size;

    seg_offsets_kernel<<<cdiv(E + 1, 256), 256, 0, stream>>>(edge_seg, M, E, edge_off);
    seg_offsets_kernel<<<cdiv(N + 1, 256), 256, 0, stream>>>(node_seg, M, N, node_off);
    f32_to_bf16_kernel<<<cdiv(N * DIM / 4, 256), 256, 0, stream>>>(node_x, node_xb, N * DIM / 4);
    swizzle_w_kernel<<<32, 256, 0, stream>>>(W_e, W_n, wsw);

    const unsigned short* xcur = node_xb;
    for (int i = 0; i < L; ++i) {
        seg_mean_bf16_kernel<<<cdiv(E, 4), 256, 0, stream>>>(
            (const unsigned int*)xcur, nodes_map, edge_off, (unsigned int*)exb, E);
        gemm_ln_relu_kernel<<<cdiv(E, ROWS_PER_BLOCK), 256, 0, stream>>>(
            exb, exb, wsw + (size_t)i * 16384, b_e + i * DIM, g_e + i * DIM, be_e + i * DIM, E);
        seg_mean_bf16_kernel<<<cdiv(N, 4), 256, 0, stream>>>(
            (const unsigned int*)exb, edges_map, node_off, (unsigned int*)xb, N);
        gemm_ln_relu_kernel<<<cdiv(N, ROWS_PER_BLOCK), 256, 0, stream>>>(
            xb, xb, wsw + (size_t)(2 + i) * 16384, b_n + i * DIM, g_n + i * DIM, be_n + i * DIM, N);
        xcur = xb;
    }

    classifier_logsoftmax_v2_kernel<<<cdiv(N, 256), 256, 0, stream>>>(xcur, W_c, b_c, out, N);
}

// Round 5
// 492.917 us; speedup vs baseline: 3.6365x; 1.2912x over previous
//
#include <hip/hip_runtime.h>
#include <hip/hip_bf16.h>

#define DIM 128

typedef __bf16 bf16x8 __attribute__((ext_vector_type(8)));
typedef float f32x4 __attribute__((ext_vector_type(4)));

static inline int cdiv(int a, int b) { return (a + b - 1) / b; }
static inline size_t align256(size_t x) { return (x + 255) & ~size_t(255); }

__device__ inline unsigned short f2bf(float f) {
    union { float f; unsigned int u; } v; v.f = f;
    unsigned int r = v.u + 0x7fff + ((v.u >> 16) & 1);   // RNE
    return (unsigned short)(r >> 16);
}
__device__ inline float bf2f(unsigned short h) {
    union { unsigned int u; float f; } v; v.u = ((unsigned int)h) << 16;
    return v.f;
}

// -------- kernel 1: segment offsets via binary search (seg sorted ascending)
__global__ void seg_offsets_kernel(const int* __restrict__ seg, int m, int nseg,
                                   int* __restrict__ off) {
    int s = blockIdx.x * blockDim.x + threadIdx.x;
    if (s > nseg) return;
    int lo = 0, hi = m;
    while (lo < hi) {
        int mid = (lo + hi) >> 1;
        if (seg[mid] < s) lo = mid + 1; else hi = mid;
    }
    off[s] = lo;
}

// -------- kernel 2: fp32 -> bf16 convert (node_x), float4 granularity
__global__ void f32_to_bf16_kernel(const float* __restrict__ in,
                                   unsigned short* __restrict__ out, int n4) {
    int i = blockIdx.x * blockDim.x + threadIdx.x;
    if (i >= n4) return;
    float4 v = ((const float4*)in)[i];
    ushort4 o;
    o.x = f2bf(v.x); o.y = f2bf(v.y); o.z = f2bf(v.z); o.w = f2bf(v.w);
    ((ushort4*)out)[i] = o;
}

// -------- kernel 3: pre-swizzle W (4 matrices of 128x128 fp32) into frag-major bf16.
// Entry e=(t,n,lane): 8 bf16 = W[t*32 + (lane>>4)*8 + j][n*16 + (lane&15)], j=0..7.
__global__ void swizzle_w_kernel(const float* __restrict__ W_e, const float* __restrict__ W_n,
                                 unsigned short* __restrict__ wsw) {
    int gid = blockIdx.x * blockDim.x + threadIdx.x;  // 4 * 2048 threads
    int mi = gid >> 11;
    int e = gid & 2047;
    const float* W = (mi < 2) ? (W_e + (size_t)mi * DIM * DIM)
                              : (W_n + (size_t)(mi - 2) * DIM * DIM);
    int t = e >> 9, n = (e >> 6) & 7, lane = e & 63;
    int q = lane >> 4, c = lane & 15;
    int k0 = t * 32 + q * 8, col = n * 16 + c;
    unsigned short vals[8];
#pragma unroll
    for (int j = 0; j < 8; ++j) vals[j] = f2bf(W[(size_t)(k0 + j) * DIM + col]);
    ushort4* dst = (ushort4*)(wsw + (size_t)gid * 8);
    dst[0] = make_ushort4(vals[0], vals[1], vals[2], vals[3]);
    dst[1] = make_ushort4(vals[4], vals[5], vals[6], vals[7]);
}

// -------- kernel 4: gather + segment mean on bf16 rows. One wave per segment.
// Software-pipelined: 4 independent row loads in flight per wave; predicated tail
// loads into zero-init regs (bf2f(0)==0) so all loads issue before accumulation.
__global__ __launch_bounds__(256)
void seg_mean_bf16_kernel(const unsigned int* __restrict__ src32, const int* __restrict__ map,
                          const int* __restrict__ off, unsigned int* __restrict__ dst32,
                          int nseg) {
    int w = threadIdx.x >> 6, lane = threadIdx.x & 63;
    int s = blockIdx.x * 4 + w;
    if (s >= nseg) return;
    int beg = off[s], end = off[s + 1];
    const unsigned int* src = src32 + lane;
    float a0 = 0.f, a1 = 0.f;
    int j = beg;
    for (; j + 4 <= end; j += 4) {
        int r0 = map[j], r1 = map[j + 1], r2 = map[j + 2], r3 = map[j + 3];
        unsigned int v0 = src[(size_t)r0 * 64];
        unsigned int v1 = src[(size_t)r1 * 64];
        unsigned int v2 = src[(size_t)r2 * 64];
        unsigned int v3 = src[(size_t)r3 * 64];
        a0 += bf2f((unsigned short)(v0 & 0xffffu)) + bf2f((unsigned short)(v1 & 0xffffu))
            + bf2f((unsigned short)(v2 & 0xffffu)) + bf2f((unsigned short)(v3 & 0xffffu));
        a1 += bf2f((unsigned short)(v0 >> 16)) + bf2f((unsigned short)(v1 >> 16))
            + bf2f((unsigned short)(v2 >> 16)) + bf2f((unsigned short)(v3 >> 16));
    }
    {   // tail 0..3: predicated independent loads, zeros are additive identity
        int rem = end - j;
        unsigned int v0 = 0, v1 = 0, v2 = 0;
        if (rem > 0) v0 = src[(size_t)map[j] * 64];
        if (rem > 1) v1 = src[(size_t)map[j + 1] * 64];
        if (rem > 2) v2 = src[(size_t)map[j + 2] * 64];
        a0 += bf2f((unsigned short)(v0 & 0xffffu)) + bf2f((unsigned short)(v1 & 0xffffu))
            + bf2f((unsigned short)(v2 & 0xffffu));
        a1 += bf2f((unsigned short)(v0 >> 16)) + bf2f((unsigned short)(v1 >> 16))
            + bf2f((unsigned short)(v2 >> 16));
    }
    float inv = 1.f / fmaxf((float)(end - beg), 1.f);
    unsigned int o = (unsigned int)f2bf(a0 * inv) | ((unsigned int)f2bf(a1 * inv) << 16);
    dst32[(size_t)s * 64 + lane] = o;
}

// -------- kernel 5: Y = relu(LN(X @ W + b) * g + be), bf16 in/out, MFMA 16x16x32.
// 4 waves/block; wave handles OT*RT*16 = 64 rows; block = 256 rows. In-place safe.
#define GEMM_OT 2
#define GEMM_RT 2
#define ROWS_PER_BLOCK 256

__global__ __launch_bounds__(256)
void gemm_ln_relu_kernel(const unsigned short* __restrict__ X, unsigned short* __restrict__ Y,
                         const unsigned short* __restrict__ Wsw, const float* __restrict__ b,
                         const float* __restrict__ g, const float* __restrict__ be,
                         int nrows) {
    __shared__ bf16x8 wlds[2048];   // 32 KB, frag-major: [(t*8+n)*64 + lane]
    int tid = threadIdx.x;
    int w = tid >> 6, lane = tid & 63;
    int q = lane >> 4, c = lane & 15;

    {   // stage swizzled W (global layout == LDS layout)
        const uint4* gsrc = (const uint4*)Wsw;
        uint4* ldst = (uint4*)wlds;
#pragma unroll
        for (int i = 0; i < 8; ++i) ldst[tid + i * 256] = gsrc[tid + i * 256];
    }
    __syncthreads();

    float bcol[8], gcol[8], becol[8];
#pragma unroll
    for (int n = 0; n < 8; ++n) {
        int col = n * 16 + c;
        bcol[n] = b[col]; gcol[n] = g[col]; becol[n] = be[col];
    }

    long base = (long)blockIdx.x * ROWS_PER_BLOCK + w * (GEMM_OT * GEMM_RT * 16);

    for (int ot = 0; ot < GEMM_OT; ++ot) {
        long tbase = base + ot * (GEMM_RT * 16);

        bf16x8 a[GEMM_RT][4];
#pragma unroll
        for (int rt = 0; rt < GEMM_RT; ++rt) {
            long rowA = tbase + rt * 16 + c;
            if (rowA > nrows - 1) rowA = nrows - 1;
            const bf16x8* ap = (const bf16x8*)(X + rowA * DIM + q * 8);
#pragma unroll
            for (int t = 0; t < 4; ++t) a[rt][t] = ap[t * 4];   // k-offset t*32 elems
        }

        f32x4 acc[GEMM_RT][8];
#pragma unroll
        for (int rt = 0; rt < GEMM_RT; ++rt)
#pragma unroll
            for (int n = 0; n < 8; ++n) acc[rt][n] = f32x4{0.f, 0.f, 0.f, 0.f};

#pragma unroll
        for (int n = 0; n < 8; ++n)
#pragma unroll
            for (int t = 0; t < 4; ++t) {
                bf16x8 bf = wlds[(t * 8 + n) * 64 + lane];
#pragma unroll
                for (int rt = 0; rt < GEMM_RT; ++rt)
                    acc[rt][n] = __builtin_amdgcn_mfma_f32_16x16x32_bf16(
                        a[rt][t], bf, acc[rt][n], 0, 0, 0);
            }

#pragma unroll
        for (int rt = 0; rt < GEMM_RT; ++rt) {
#pragma unroll
            for (int n = 0; n < 8; ++n)
#pragma unroll
                for (int j = 0; j < 4; ++j) acc[rt][n][j] += bcol[n];

            // per-row mean/var; lane's 4 rows = tbase + rt*16 + q*4 + j
            float s1[4], s2[4];
#pragma unroll
            for (int j = 0; j < 4; ++j) {
                float t1 = 0.f, t2 = 0.f;
#pragma unroll
                for (int n = 0; n < 8; ++n) { float v = acc[rt][n][j]; t1 += v; t2 += v * v; }
                s1[j] = t1; s2[j] = t2;
            }
#pragma unroll
            for (int o = 1; o < 16; o <<= 1)
#pragma unroll
                for (int j = 0; j < 4; ++j) {
                    s1[j] += __shfl_xor(s1[j], o);
                    s2[j] += __shfl_xor(s2[j], o);
                }
#pragma unroll
            for (int j = 0; j < 4; ++j) {
                long row = tbase + rt * 16 + q * 4 + j;
                if (row >= nrows) continue;
                float m = s1[j] * (1.f / DIM);
                float v = s2[j] * (1.f / DIM) - m * m;
                float inv = rsqrtf(v + 1e-5f);
#pragma unroll
                for (int n = 0; n < 8; ++n) {
                    float y = (acc[rt][n][j] - m) * inv * gcol[n] + becol[n];
                    Y[row * DIM + n * 16 + c] = f2bf(fmaxf(y, 0.f));
                }
            }
        }
    }
}

// -------- kernel 6: classifier + log_softmax, thread-per-row. Row = 16 uint4.
__global__ __launch_bounds__(256)
void classifier_logsoftmax_v2_kernel(const unsigned short* __restrict__ X,
                                     const float* __restrict__ Wc,
                                     const float* __restrict__ bc,
                                     float* __restrict__ out, int nrows) {
    int r = blockIdx.x * 256 + threadIdx.x;
    if (r >= nrows) return;

    uint4 rowv[16];
    const uint4* xp = (const uint4*)(X + (size_t)r * DIM);
#pragma unroll
    for (int i = 0; i < 16; ++i) rowv[i] = xp[i];
    const unsigned int* ru = (const unsigned int*)rowv;

    float acc[10];
#pragma unroll
    for (int c = 0; c < 10; ++c) acc[c] = bc[c];

#pragma unroll 8
    for (int j = 0; j < 64; ++j) {
        unsigned int u = ru[j];
        float x0 = bf2f((unsigned short)(u & 0xffffu));
        float x1 = bf2f((unsigned short)(u >> 16));
#pragma unroll
        for (int c = 0; c < 10; ++c)
            acc[c] += x0 * Wc[(2 * j) * 10 + c] + x1 * Wc[(2 * j + 1) * 10 + c];
    }

    float mx = acc[0];
#pragma unroll
    for (int c = 1; c < 10; ++c) mx = fmaxf(mx, acc[c]);
    float se = 0.f;
#pragma unroll
    for (int c = 0; c < 10; ++c) se += expf(acc[c] - mx);
    float lse = mx + logf(se);
    float* op = out + (size_t)r * 10;
#pragma unroll
    for (int c = 0; c < 10; ++c) op[c] = acc[c] - lse;
}

extern "C" void kernel_launch(void* const* d_in, const int* in_sizes, int n_in,
                              void* d_out, int out_size, void* d_ws, size_t ws_size,
                              hipStream_t stream) {
    const float* node_x    = (const float*)d_in[0];
    const int*   nodes_map = (const int*)d_in[1];
    const int*   edge_seg  = (const int*)d_in[2];
    const int*   edges_map = (const int*)d_in[3];
    const int*   node_seg  = (const int*)d_in[4];
    const float* W_e = (const float*)d_in[6];
    const float* b_e = (const float*)d_in[7];
    const float* g_e = (const float*)d_in[8];
    const float* be_e= (const float*)d_in[9];
    const float* W_n = (const float*)d_in[10];
    const float* b_n = (const float*)d_in[11];
    const float* g_n = (const float*)d_in[12];
    const float* be_n= (const float*)d_in[13];
    const float* W_c = (const float*)d_in[14];
    const float* b_c = (const float*)d_in[15];
    float* out = (float*)d_out;

    const int N = in_sizes[0] / DIM;           // 100000
    const int M = in_sizes[1];                 // 800000
    const int E = 200000;                      // N_EDGES (problem constant)
    const int L = in_sizes[6] / (DIM * DIM);   // 2

    // workspace carve-up
    char* ws = (char*)d_ws;
    int* edge_off = (int*)ws;           ws += align256((size_t)(E + 1) * sizeof(int));
    int* node_off = (int*)ws;           ws += align256((size_t)(N + 1) * sizeof(int));
    unsigned short* wsw = (unsigned short*)ws;      ws += align256((size_t)4 * 2048 * 8 * sizeof(unsigned short));
    unsigned short* node_xb = (unsigned short*)ws;  ws += align256((size_t)N * DIM * sizeof(unsigned short));
    unsigned short* exb = (unsigned short*)ws;      ws += align256((size_t)E * DIM * sizeof(unsigned short));
    unsigned short* xb  = (unsigned short*)ws;      ws += align256((size_t)N * DIM * sizeof(unsigned short));
    (void)ws_size;

    seg_offsets_kernel<<<cdiv(E + 1, 256), 256, 0, stream>>>(edge_seg, M, E, edge_off);
    seg_offsets_kernel<<<cdiv(N + 1, 256), 256, 0, stream>>>(node_seg, M, N, node_off);
    f32_to_bf16_kernel<<<cdiv(N * DIM / 4, 256), 256, 0, stream>>>(node_x, node_xb, N * DIM / 4);
    swizzle_w_kernel<<<32, 256, 0, stream>>>(W_e, W_n, wsw);

    const unsigned short* xcur = node_xb;
    for (int i = 0; i < L; ++i) {
        seg_mean_bf16_kernel<<<cdiv(E, 4), 256, 0, stream>>>(
            (const unsigned int*)xcur, nodes_map, edge_off, (unsigned int*)exb, E);
        gemm_ln_relu_kernel<<<cdiv(E, ROWS_PER_BLOCK), 256, 0, stream>>>(
            exb, exb, wsw + (size_t)i * 16384, b_e + i * DIM, g_e + i * DIM, be_e + i * DIM, E);
        seg_mean_bf16_kernel<<<cdiv(N, 4), 256, 0, stream>>>(
            (const unsigned int*)exb, edges_map, node_off, (unsigned int*)xb, N);
        gemm_ln_relu_kernel<<<cdiv(N, ROWS_PER_BLOCK), 256, 0, stream>>>(
            xb, xb, wsw + (size_t)(2 + i) * 16384, b_n + i * DIM, g_n + i * DIM, be_n + i * DIM, N);
        xcur = xb;
    }

    classifier_logsoftmax_v2_kernel<<<cdiv(N, 256), 256, 0, stream>>>(xcur, W_c, b_c, out, N);
}

// Round 6
// 418.022 us; speedup vs baseline: 4.2881x; 1.1792x over previous
//
#include <hip/hip_runtime.h>
#include <hip/hip_bf16.h>

#define DIM 128

typedef __bf16 bf16x8 __attribute__((ext_vector_type(8)));
typedef float f32x4 __attribute__((ext_vector_type(4)));

static inline int cdiv(int a, int b) { return (a + b - 1) / b; }
static inline size_t align256(size_t x) { return (x + 255) & ~size_t(255); }

__device__ inline unsigned short f2bf(float f) {
    union { float f; unsigned int u; } v; v.f = f;
    unsigned int r = v.u + 0x7fff + ((v.u >> 16) & 1);   // RNE
    return (unsigned short)(r >> 16);
}
__device__ inline float bf2f(unsigned short h) {
    union { unsigned int u; float f; } v; v.u = ((unsigned int)h) << 16;
    return v.f;
}

// -------- kernel 1: segment offsets via binary search (seg sorted ascending)
__global__ void seg_offsets_kernel(const int* __restrict__ seg, int m, int nseg,
                                   int* __restrict__ off) {
    int s = blockIdx.x * blockDim.x + threadIdx.x;
    if (s > nseg) return;
    int lo = 0, hi = m;
    while (lo < hi) {
        int mid = (lo + hi) >> 1;
        if (seg[mid] < s) lo = mid + 1; else hi = mid;
    }
    off[s] = lo;
}

// -------- kernel 2: fp32 -> bf16 convert (node_x), float4 granularity
__global__ void f32_to_bf16_kernel(const float* __restrict__ in,
                                   unsigned short* __restrict__ out, int n4) {
    int i = blockIdx.x * blockDim.x + threadIdx.x;
    if (i >= n4) return;
    float4 v = ((const float4*)in)[i];
    ushort4 o;
    o.x = f2bf(v.x); o.y = f2bf(v.y); o.z = f2bf(v.z); o.w = f2bf(v.w);
    ((ushort4*)out)[i] = o;
}

// -------- kernel 3: pre-swizzle W (4 matrices of 128x128 fp32) into frag-major bf16.
// Entry e=(t,n,lane): 8 bf16 = W[t*32 + (lane>>4)*8 + j][n*16 + (lane&15)], j=0..7.
__global__ void swizzle_w_kernel(const float* __restrict__ W_e, const float* __restrict__ W_n,
                                 unsigned short* __restrict__ wsw) {
    int gid = blockIdx.x * blockDim.x + threadIdx.x;  // 4 * 2048 threads
    int mi = gid >> 11;
    int e = gid & 2047;
    const float* W = (mi < 2) ? (W_e + (size_t)mi * DIM * DIM)
                              : (W_n + (size_t)(mi - 2) * DIM * DIM);
    int t = e >> 9, n = (e >> 6) & 7, lane = e & 63;
    int q = lane >> 4, c = lane & 15;
    int k0 = t * 32 + q * 8, col = n * 16 + c;
    unsigned short vals[8];
#pragma unroll
    for (int j = 0; j < 8; ++j) vals[j] = f2bf(W[(size_t)(k0 + j) * DIM + col]);
    ushort4* dst = (ushort4*)(wsw + (size_t)gid * 8);
    dst[0] = make_ushort4(vals[0], vals[1], vals[2], vals[3]);
    dst[1] = make_ushort4(vals[4], vals[5], vals[6], vals[7]);
}

// -------- kernel 4 v2: gather + segment mean, 4 segments per wave.
// Quarter-wave (16 lanes) per segment; lane reads a contiguous uint4 (16 B = 8 bf16
// cols) per member row -> full 256 B row per quarter, 16 outstanding loads per wave.
// Intra-batch tail: clamp index (hot L2 line) + weight-0 FMA. Divergent trip counts
// across quarters just idle finished quarters.
__device__ inline void accum8(float* a, uint4 v, float wt) {
    unsigned int u[4] = {v.x, v.y, v.z, v.w};
#pragma unroll
    for (int i = 0; i < 4; ++i) {
        union { unsigned int ui; float f; } lo, hi;
        lo.ui = u[i] << 16;
        hi.ui = u[i] & 0xffff0000u;
        a[2 * i]     = fmaf(wt, lo.f, a[2 * i]);
        a[2 * i + 1] = fmaf(wt, hi.f, a[2 * i + 1]);
    }
}

__global__ __launch_bounds__(256)
void seg_mean_bf16_v2_kernel(const uint4* __restrict__ src, const int* __restrict__ map,
                             const int* __restrict__ off, uint4* __restrict__ dst,
                             int nseg) {
    int w = threadIdx.x >> 6, lane = threadIdx.x & 63;
    int g = lane >> 4, c16 = lane & 15;
    int s = blockIdx.x * 16 + w * 4 + g;
    int sc = min(s, nseg - 1);
    int beg = off[sc], end = off[sc + 1];

    float a[8] = {0.f, 0.f, 0.f, 0.f, 0.f, 0.f, 0.f, 0.f};

    for (int j = beg; j < end; j += 4) {
        int j1 = min(j + 1, end - 1), j2 = min(j + 2, end - 1), j3 = min(j + 3, end - 1);
        int r0 = map[j], r1 = map[j1], r2 = map[j2], r3 = map[j3];
        uint4 v0 = src[(size_t)r0 * 16 + c16];
        uint4 v1 = src[(size_t)r1 * 16 + c16];
        uint4 v2 = src[(size_t)r2 * 16 + c16];
        uint4 v3 = src[(size_t)r3 * 16 + c16];
        float w1 = (j + 1 < end) ? 1.f : 0.f;
        float w2 = (j + 2 < end) ? 1.f : 0.f;
        float w3 = (j + 3 < end) ? 1.f : 0.f;
        accum8(a, v0, 1.f);
        accum8(a, v1, w1);
        accum8(a, v2, w2);
        accum8(a, v3, w3);
    }

    if (s < nseg) {
        float inv = 1.f / fmaxf((float)(end - beg), 1.f);
        uint4 o;
        o.x = (unsigned int)f2bf(a[0] * inv) | ((unsigned int)f2bf(a[1] * inv) << 16);
        o.y = (unsigned int)f2bf(a[2] * inv) | ((unsigned int)f2bf(a[3] * inv) << 16);
        o.z = (unsigned int)f2bf(a[4] * inv) | ((unsigned int)f2bf(a[5] * inv) << 16);
        o.w = (unsigned int)f2bf(a[6] * inv) | ((unsigned int)f2bf(a[7] * inv) << 16);
        dst[(size_t)s * 16 + c16] = o;
    }
}

// -------- kernel 5: Y = relu(LN(X @ W + b) * g + be), bf16 in/out, MFMA 16x16x32.
// 4 waves/block; wave handles OT*RT*16 = 64 rows; block = 256 rows. In-place safe.
#define GEMM_OT 2
#define GEMM_RT 2
#define ROWS_PER_BLOCK 256

__global__ __launch_bounds__(256)
void gemm_ln_relu_kernel(const unsigned short* __restrict__ X, unsigned short* __restrict__ Y,
                         const unsigned short* __restrict__ Wsw, const float* __restrict__ b,
                         const float* __restrict__ g, const float* __restrict__ be,
                         int nrows) {
    __shared__ bf16x8 wlds[2048];   // 32 KB, frag-major: [(t*8+n)*64 + lane]
    int tid = threadIdx.x;
    int w = tid >> 6, lane = tid & 63;
    int q = lane >> 4, c = lane & 15;

    {   // stage swizzled W (global layout == LDS layout)
        const uint4* gsrc = (const uint4*)Wsw;
        uint4* ldst = (uint4*)wlds;
#pragma unroll
        for (int i = 0; i < 8; ++i) ldst[tid + i * 256] = gsrc[tid + i * 256];
    }
    __syncthreads();

    float bcol[8], gcol[8], becol[8];
#pragma unroll
    for (int n = 0; n < 8; ++n) {
        int col = n * 16 + c;
        bcol[n] = b[col]; gcol[n] = g[col]; becol[n] = be[col];
    }

    long base = (long)blockIdx.x * ROWS_PER_BLOCK + w * (GEMM_OT * GEMM_RT * 16);

    for (int ot = 0; ot < GEMM_OT; ++ot) {
        long tbase = base + ot * (GEMM_RT * 16);

        bf16x8 a[GEMM_RT][4];
#pragma unroll
        for (int rt = 0; rt < GEMM_RT; ++rt) {
            long rowA = tbase + rt * 16 + c;
            if (rowA > nrows - 1) rowA = nrows - 1;
            const bf16x8* ap = (const bf16x8*)(X + rowA * DIM + q * 8);
#pragma unroll
            for (int t = 0; t < 4; ++t) a[rt][t] = ap[t * 4];   // k-offset t*32 elems
        }

        f32x4 acc[GEMM_RT][8];
#pragma unroll
        for (int rt = 0; rt < GEMM_RT; ++rt)
#pragma unroll
            for (int n = 0; n < 8; ++n) acc[rt][n] = f32x4{0.f, 0.f, 0.f, 0.f};

#pragma unroll
        for (int n = 0; n < 8; ++n)
#pragma unroll
            for (int t = 0; t < 4; ++t) {
                bf16x8 bf = wlds[(t * 8 + n) * 64 + lane];
#pragma unroll
                for (int rt = 0; rt < GEMM_RT; ++rt)
                    acc[rt][n] = __builtin_amdgcn_mfma_f32_16x16x32_bf16(
                        a[rt][t], bf, acc[rt][n], 0, 0, 0);
            }

#pragma unroll
        for (int rt = 0; rt < GEMM_RT; ++rt) {
#pragma unroll
            for (int n = 0; n < 8; ++n)
#pragma unroll
                for (int j = 0; j < 4; ++j) acc[rt][n][j] += bcol[n];

            // per-row mean/var; lane's 4 rows = tbase + rt*16 + q*4 + j
            float s1[4], s2[4];
#pragma unroll
            for (int j = 0; j < 4; ++j) {
                float t1 = 0.f, t2 = 0.f;
#pragma unroll
                for (int n = 0; n < 8; ++n) { float v = acc[rt][n][j]; t1 += v; t2 += v * v; }
                s1[j] = t1; s2[j] = t2;
            }
#pragma unroll
            for (int o = 1; o < 16; o <<= 1)
#pragma unroll
                for (int j = 0; j < 4; ++j) {
                    s1[j] += __shfl_xor(s1[j], o);
                    s2[j] += __shfl_xor(s2[j], o);
                }
#pragma unroll
            for (int j = 0; j < 4; ++j) {
                long row = tbase + rt * 16 + q * 4 + j;
                if (row >= nrows) continue;
                float m = s1[j] * (1.f / DIM);
                float v = s2[j] * (1.f / DIM) - m * m;
                float inv = rsqrtf(v + 1e-5f);
#pragma unroll
                for (int n = 0; n < 8; ++n) {
                    float y = (acc[rt][n][j] - m) * inv * gcol[n] + becol[n];
                    Y[row * DIM + n * 16 + c] = f2bf(fmaxf(y, 0.f));
                }
            }
        }
    }
}

// -------- kernel 6: classifier + log_softmax, thread-per-row. Row = 16 uint4.
__global__ __launch_bounds__(256)
void classifier_logsoftmax_v2_kernel(const unsigned short* __restrict__ X,
                                     const float* __restrict__ Wc,
                                     const float* __restrict__ bc,
                                     float* __restrict__ out, int nrows) {
    int r = blockIdx.x * 256 + threadIdx.x;
    if (r >= nrows) return;

    uint4 rowv[16];
    const uint4* xp = (const uint4*)(X + (size_t)r * DIM);
#pragma unroll
    for (int i = 0; i < 16; ++i) rowv[i] = xp[i];
    const unsigned int* ru = (const unsigned int*)rowv;

    float acc[10];
#pragma unroll
    for (int c = 0; c < 10; ++c) acc[c] = bc[c];

#pragma unroll 8
    for (int j = 0; j < 64; ++j) {
        unsigned int u = ru[j];
        float x0 = bf2f((unsigned short)(u & 0xffffu));
        float x1 = bf2f((unsigned short)(u >> 16));
#pragma unroll
        for (int c = 0; c < 10; ++c)
            acc[c] += x0 * Wc[(2 * j) * 10 + c] + x1 * Wc[(2 * j + 1) * 10 + c];
    }

    float mx = acc[0];
#pragma unroll
    for (int c = 1; c < 10; ++c) mx = fmaxf(mx, acc[c]);
    float se = 0.f;
#pragma unroll
    for (int c = 0; c < 10; ++c) se += expf(acc[c] - mx);
    float lse = mx + logf(se);
    float* op = out + (size_t)r * 10;
#pragma unroll
    for (int c = 0; c < 10; ++c) op[c] = acc[c] - lse;
}

extern "C" void kernel_launch(void* const* d_in, const int* in_sizes, int n_in,
                              void* d_out, int out_size, void* d_ws, size_t ws_size,
                              hipStream_t stream) {
    const float* node_x    = (const float*)d_in[0];
    const int*   nodes_map = (const int*)d_in[1];
    const int*   edge_seg  = (const int*)d_in[2];
    const int*   edges_map = (const int*)d_in[3];
    const int*   node_seg  = (const int*)d_in[4];
    const float* W_e = (const float*)d_in[6];
    const float* b_e = (const float*)d_in[7];
    const float* g_e = (const float*)d_in[8];
    const float* be_e= (const float*)d_in[9];
    const float* W_n = (const float*)d_in[10];
    const float* b_n = (const float*)d_in[11];
    const float* g_n = (const float*)d_in[12];
    const float* be_n= (const float*)d_in[13];
    const float* W_c = (const float*)d_in[14];
    const float* b_c = (const float*)d_in[15];
    float* out = (float*)d_out;

    const int N = in_sizes[0] / DIM;           // 100000
    const int M = in_sizes[1];                 // 800000
    const int E = 200000;                      // N_EDGES (problem constant)
    const int L = in_sizes[6] / (DIM * DIM);   // 2

    // workspace carve-up
    char* ws = (char*)d_ws;
    int* edge_off = (int*)ws;           ws += align256((size_t)(E + 1) * sizeof(int));
    int* node_off = (int*)ws;           ws += align256((size_t)(N + 1) * sizeof(int));
    unsigned short* wsw = (unsigned short*)ws;      ws += align256((size_t)4 * 2048 * 8 * sizeof(unsigned short));
    unsigned short* node_xb = (unsigned short*)ws;  ws += align256((size_t)N * DIM * sizeof(unsigned short));
    unsigned short* exb = (unsigned short*)ws;      ws += align256((size_t)E * DIM * sizeof(unsigned short));
    unsigned short* xb  = (unsigned short*)ws;      ws += align256((size_t)N * DIM * sizeof(unsigned short));
    (void)ws_size;

    seg_offsets_kernel<<<cdiv(E + 1, 256), 256, 0, stream>>>(edge_seg, M, E, edge_off);
    seg_offsets_kernel<<<cdiv(N + 1, 256), 256, 0, stream>>>(node_seg, M, N, node_off);
    f32_to_bf16_kernel<<<cdiv(N * DIM / 4, 256), 256, 0, stream>>>(node_x, node_xb, N * DIM / 4);
    swizzle_w_kernel<<<32, 256, 0, stream>>>(W_e, W_n, wsw);

    const unsigned short* xcur = node_xb;
    for (int i = 0; i < L; ++i) {
        seg_mean_bf16_v2_kernel<<<cdiv(E, 16), 256, 0, stream>>>(
            (const uint4*)xcur, nodes_map, edge_off, (uint4*)exb, E);
        gemm_ln_relu_kernel<<<cdiv(E, ROWS_PER_BLOCK), 256, 0, stream>>>(
            exb, exb, wsw + (size_t)i * 16384, b_e + i * DIM, g_e + i * DIM, be_e + i * DIM, E);
        seg_mean_bf16_v2_kernel<<<cdiv(N, 16), 256, 0, stream>>>(
            (const uint4*)exb, edges_map, node_off, (uint4*)xb, N);
        gemm_ln_relu_kernel<<<cdiv(N, ROWS_PER_BLOCK), 256, 0, stream>>>(
            xb, xb, wsw + (size_t)(2 + i) * 16384, b_n + i * DIM, g_n + i * DIM, be_n + i * DIM, N);
        xcur = xb;
    }

    classifier_logsoftmax_v2_kernel<<<cdiv(N, 256), 256, 0, stream>>>(xcur, W_c, b_c, out, N);
}

// Round 7
// 407.442 us; speedup vs baseline: 4.3994x; 1.0260x over previous
//
#include <hip/hip_runtime.h>
#include <hip/hip_bf16.h>

#define DIM 128

typedef __bf16 bf16x8 __attribute__((ext_vector_type(8)));
typedef float f32x4 __attribute__((ext_vector_type(4)));

static inline int cdiv(int a, int b) { return (a + b - 1) / b; }
static inline size_t align256(size_t x) { return (x + 255) & ~size_t(255); }

__device__ inline unsigned short f2bf(float f) {
    union { float f; unsigned int u; } v; v.f = f;
    unsigned int r = v.u + 0x7fff + ((v.u >> 16) & 1);   // RNE
    return (unsigned short)(r >> 16);
}
__device__ inline float bf2f(unsigned short h) {
    union { unsigned int u; float f; } v; v.u = ((unsigned int)h) << 16;
    return v.f;
}

// -------- kernel 1: segment offsets via binary search (seg sorted ascending)
__global__ void seg_offsets_kernel(const int* __restrict__ seg, int m, int nseg,
                                   int* __restrict__ off) {
    int s = blockIdx.x * blockDim.x + threadIdx.x;
    if (s > nseg) return;
    int lo = 0, hi = m;
    while (lo < hi) {
        int mid = (lo + hi) >> 1;
        if (seg[mid] < s) lo = mid + 1; else hi = mid;
    }
    off[s] = lo;
}

// -------- kernel 2: fp32 -> bf16 convert (node_x), float4 granularity
__global__ void f32_to_bf16_kernel(const float* __restrict__ in,
                                   unsigned short* __restrict__ out, int n4) {
    int i = blockIdx.x * blockDim.x + threadIdx.x;
    if (i >= n4) return;
    float4 v = ((const float4*)in)[i];
    ushort4 o;
    o.x = f2bf(v.x); o.y = f2bf(v.y); o.z = f2bf(v.z); o.w = f2bf(v.w);
    ((ushort4*)out)[i] = o;
}

// -------- kernel 3: pre-swizzle W (4 matrices of 128x128 fp32) into frag-major bf16.
// Entry e=(t,n,lane): 8 bf16 = W[t*32 + (lane>>4)*8 + j][n*16 + (lane&15)], j=0..7.
__global__ void swizzle_w_kernel(const float* __restrict__ W_e, const float* __restrict__ W_n,
                                 unsigned short* __restrict__ wsw) {
    int gid = blockIdx.x * blockDim.x + threadIdx.x;  // 4 * 2048 threads
    int mi = gid >> 11;
    int e = gid & 2047;
    const float* W = (mi < 2) ? (W_e + (size_t)mi * DIM * DIM)
                              : (W_n + (size_t)(mi - 2) * DIM * DIM);
    int t = e >> 9, n = (e >> 6) & 7, lane = e & 63;
    int q = lane >> 4, c = lane & 15;
    int k0 = t * 32 + q * 8, col = n * 16 + c;
    unsigned short vals[8];
#pragma unroll
    for (int j = 0; j < 8; ++j) vals[j] = f2bf(W[(size_t)(k0 + j) * DIM + col]);
    ushort4* dst = (ushort4*)(wsw + (size_t)gid * 8);
    dst[0] = make_ushort4(vals[0], vals[1], vals[2], vals[3]);
    dst[1] = make_ushort4(vals[4], vals[5], vals[6], vals[7]);
}

// -------- kernel 4 v2: gather + segment mean, 4 segments per wave.
// Quarter-wave (16 lanes) per segment; lane reads a contiguous uint4 per member row.
__device__ inline void accum8(float* a, uint4 v, float wt) {
    unsigned int u[4] = {v.x, v.y, v.z, v.w};
#pragma unroll
    for (int i = 0; i < 4; ++i) {
        union { unsigned int ui; float f; } lo, hi;
        lo.ui = u[i] << 16;
        hi.ui = u[i] & 0xffff0000u;
        a[2 * i]     = fmaf(wt, lo.f, a[2 * i]);
        a[2 * i + 1] = fmaf(wt, hi.f, a[2 * i + 1]);
    }
}

__global__ __launch_bounds__(256)
void seg_mean_bf16_v2_kernel(const uint4* __restrict__ src, const int* __restrict__ map,
                             const int* __restrict__ off, uint4* __restrict__ dst,
                             int nseg) {
    int w = threadIdx.x >> 6, lane = threadIdx.x & 63;
    int g = lane >> 4, c16 = lane & 15;
    int s = blockIdx.x * 16 + w * 4 + g;
    int sc = min(s, nseg - 1);
    int beg = off[sc], end = off[sc + 1];

    float a[8] = {0.f, 0.f, 0.f, 0.f, 0.f, 0.f, 0.f, 0.f};

    for (int j = beg; j < end; j += 4) {
        int j1 = min(j + 1, end - 1), j2 = min(j + 2, end - 1), j3 = min(j + 3, end - 1);
        int r0 = map[j], r1 = map[j1], r2 = map[j2], r3 = map[j3];
        uint4 v0 = src[(size_t)r0 * 16 + c16];
        uint4 v1 = src[(size_t)r1 * 16 + c16];
        uint4 v2 = src[(size_t)r2 * 16 + c16];
        uint4 v3 = src[(size_t)r3 * 16 + c16];
        float w1 = (j + 1 < end) ? 1.f : 0.f;
        float w2 = (j + 2 < end) ? 1.f : 0.f;
        float w3 = (j + 3 < end) ? 1.f : 0.f;
        accum8(a, v0, 1.f);
        accum8(a, v1, w1);
        accum8(a, v2, w2);
        accum8(a, v3, w3);
    }

    if (s < nseg) {
        float inv = 1.f / fmaxf((float)(end - beg), 1.f);
        uint4 o;
        o.x = (unsigned int)f2bf(a[0] * inv) | ((unsigned int)f2bf(a[1] * inv) << 16);
        o.y = (unsigned int)f2bf(a[2] * inv) | ((unsigned int)f2bf(a[3] * inv) << 16);
        o.z = (unsigned int)f2bf(a[4] * inv) | ((unsigned int)f2bf(a[5] * inv) << 16);
        o.w = (unsigned int)f2bf(a[6] * inv) | ((unsigned int)f2bf(a[7] * inv) << 16);
        dst[(size_t)s * 16 + c16] = o;
    }
}

// -------- kernel 5: Y = relu(LN(X @ W + b) * g + be), bf16 in/out, MFMA 16x16x32.
#define GEMM_OT 2
#define GEMM_RT 2
#define ROWS_PER_BLOCK 256

__global__ __launch_bounds__(256)
void gemm_ln_relu_kernel(const unsigned short* __restrict__ X, unsigned short* __restrict__ Y,
                         const unsigned short* __restrict__ Wsw, const float* __restrict__ b,
                         const float* __restrict__ g, const float* __restrict__ be,
                         int nrows) {
    __shared__ bf16x8 wlds[2048];   // 32 KB, frag-major: [(t*8+n)*64 + lane]
    int tid = threadIdx.x;
    int w = tid >> 6, lane = tid & 63;
    int q = lane >> 4, c = lane & 15;

    {   // stage swizzled W (global layout == LDS layout)
        const uint4* gsrc = (const uint4*)Wsw;
        uint4* ldst = (uint4*)wlds;
#pragma unroll
        for (int i = 0; i < 8; ++i) ldst[tid + i * 256] = gsrc[tid + i * 256];
    }
    __syncthreads();

    float bcol[8], gcol[8], becol[8];
#pragma unroll
    for (int n = 0; n < 8; ++n) {
        int col = n * 16 + c;
        bcol[n] = b[col]; gcol[n] = g[col]; becol[n] = be[col];
    }

    long base = (long)blockIdx.x * ROWS_PER_BLOCK + w * (GEMM_OT * GEMM_RT * 16);

    for (int ot = 0; ot < GEMM_OT; ++ot) {
        long tbase = base + ot * (GEMM_RT * 16);

        bf16x8 a[GEMM_RT][4];
#pragma unroll
        for (int rt = 0; rt < GEMM_RT; ++rt) {
            long rowA = tbase + rt * 16 + c;
            if (rowA > nrows - 1) rowA = nrows - 1;
            const bf16x8* ap = (const bf16x8*)(X + rowA * DIM + q * 8);
#pragma unroll
            for (int t = 0; t < 4; ++t) a[rt][t] = ap[t * 4];   // k-offset t*32 elems
        }

        f32x4 acc[GEMM_RT][8];
#pragma unroll
        for (int rt = 0; rt < GEMM_RT; ++rt)
#pragma unroll
            for (int n = 0; n < 8; ++n) acc[rt][n] = f32x4{0.f, 0.f, 0.f, 0.f};

#pragma unroll
        for (int n = 0; n < 8; ++n)
#pragma unroll
            for (int t = 0; t < 4; ++t) {
                bf16x8 bf = wlds[(t * 8 + n) * 64 + lane];
#pragma unroll
                for (int rt = 0; rt < GEMM_RT; ++rt)
                    acc[rt][n] = __builtin_amdgcn_mfma_f32_16x16x32_bf16(
                        a[rt][t], bf, acc[rt][n], 0, 0, 0);
            }

#pragma unroll
        for (int rt = 0; rt < GEMM_RT; ++rt) {
#pragma unroll
            for (int n = 0; n < 8; ++n)
#pragma unroll
                for (int j = 0; j < 4; ++j) acc[rt][n][j] += bcol[n];

            float s1[4], s2[4];
#pragma unroll
            for (int j = 0; j < 4; ++j) {
                float t1 = 0.f, t2 = 0.f;
#pragma unroll
                for (int n = 0; n < 8; ++n) { float v = acc[rt][n][j]; t1 += v; t2 += v * v; }
                s1[j] = t1; s2[j] = t2;
            }
#pragma unroll
            for (int o = 1; o < 16; o <<= 1)
#pragma unroll
                for (int j = 0; j < 4; ++j) {
                    s1[j] += __shfl_xor(s1[j], o);
                    s2[j] += __shfl_xor(s2[j], o);
                }
#pragma unroll
            for (int j = 0; j < 4; ++j) {
                long row = tbase + rt * 16 + q * 4 + j;
                if (row >= nrows) continue;
                float m = s1[j] * (1.f / DIM);
                float v = s2[j] * (1.f / DIM) - m * m;
                float inv = rsqrtf(v + 1e-5f);
#pragma unroll
                for (int n = 0; n < 8; ++n) {
                    float y = (acc[rt][n][j] - m) * inv * gcol[n] + becol[n];
                    Y[row * DIM + n * 16 + c] = f2bf(fmaxf(y, 0.f));
                }
            }
        }
    }
}

// -------- kernel 6 v3: classifier + log_softmax, quarter-wave per row, 4 rows/quarter.
// Lane c16 loads row chunk c16 (uint4 = 8 bf16) -> coalesced 256 B per row.
// Wc[c16*8+j][c] held in 80 VGPRs, amortized over CL_ROWS rows.
#define CL_ROWS 4
__global__ __launch_bounds__(256)
void classifier_logsoftmax_v3_kernel(const uint4* __restrict__ X,
                                     const float* __restrict__ Wc,
                                     const float* __restrict__ bc,
                                     float* __restrict__ out, int nrows) {
    int w = threadIdx.x >> 6, lane = threadIdx.x & 63;
    int g = lane >> 4, c16 = lane & 15;
    int r0 = (blockIdx.x * 16 + w * 4 + g) * CL_ROWS;
    if (r0 >= nrows) return;

    // hoist Wc rows c16*8 .. c16*8+7 (80 floats) and bc
    float wc[8][10];
#pragma unroll
    for (int j = 0; j < 8; ++j)
#pragma unroll
        for (int c = 0; c < 10; ++c) wc[j][c] = Wc[(c16 * 8 + j) * 10 + c];
    float bcv[10];
#pragma unroll
    for (int c = 0; c < 10; ++c) bcv[c] = bc[c];

    int rend = min(r0 + CL_ROWS, nrows);
    for (int r = r0; r < rend; ++r) {
        uint4 v = X[(size_t)r * 16 + c16];
        float x[8];
        {
            unsigned int u[4] = {v.x, v.y, v.z, v.w};
#pragma unroll
            for (int i = 0; i < 4; ++i) {
                union { unsigned int ui; float f; } lo, hi;
                lo.ui = u[i] << 16;
                hi.ui = u[i] & 0xffff0000u;
                x[2 * i] = lo.f; x[2 * i + 1] = hi.f;
            }
        }
        float acc[10];
#pragma unroll
        for (int c = 0; c < 10; ++c) acc[c] = 0.f;
#pragma unroll
        for (int j = 0; j < 8; ++j)
#pragma unroll
            for (int c = 0; c < 10; ++c) acc[c] = fmaf(x[j], wc[j][c], acc[c]);

        // reduce across the 16-lane quarter (offsets < 16 stay in-quarter)
#pragma unroll
        for (int o = 1; o < 16; o <<= 1)
#pragma unroll
            for (int c = 0; c < 10; ++c) acc[c] += __shfl_xor(acc[c], o);

#pragma unroll
        for (int c = 0; c < 10; ++c) acc[c] += bcv[c];

        float mx = acc[0];
#pragma unroll
        for (int c = 1; c < 10; ++c) mx = fmaxf(mx, acc[c]);
        float se = 0.f;
#pragma unroll
        for (int c = 0; c < 10; ++c) se += expf(acc[c] - mx);
        float lse = mx + logf(se);

        // lane c16<10 writes class c16
        float myv = 0.f;
#pragma unroll
        for (int c = 0; c < 10; ++c) myv = (c16 == c) ? acc[c] : myv;
        if (c16 < 10) out[(size_t)r * 10 + c16] = myv - lse;
    }
}

extern "C" void kernel_launch(void* const* d_in, const int* in_sizes, int n_in,
                              void* d_out, int out_size, void* d_ws, size_t ws_size,
                              hipStream_t stream) {
    const float* node_x    = (const float*)d_in[0];
    const int*   nodes_map = (const int*)d_in[1];
    const int*   edge_seg  = (const int*)d_in[2];
    const int*   edges_map = (const int*)d_in[3];
    const int*   node_seg  = (const int*)d_in[4];
    const float* W_e = (const float*)d_in[6];
    const float* b_e = (const float*)d_in[7];
    const float* g_e = (const float*)d_in[8];
    const float* be_e= (const float*)d_in[9];
    const float* W_n = (const float*)d_in[10];
    const float* b_n = (const float*)d_in[11];
    const float* g_n = (const float*)d_in[12];
    const float* be_n= (const float*)d_in[13];
    const float* W_c = (const float*)d_in[14];
    const float* b_c = (const float*)d_in[15];
    float* out = (float*)d_out;

    const int N = in_sizes[0] / DIM;           // 100000
    const int M = in_sizes[1];                 // 800000
    const int E = 200000;                      // N_EDGES (problem constant)
    const int L = in_sizes[6] / (DIM * DIM);   // 2

    // workspace carve-up
    char* ws = (char*)d_ws;
    int* edge_off = (int*)ws;           ws += align256((size_t)(E + 1) * sizeof(int));
    int* node_off = (int*)ws;           ws += align256((size_t)(N + 1) * sizeof(int));
    unsigned short* wsw = (unsigned short*)ws;      ws += align256((size_t)4 * 2048 * 8 * sizeof(unsigned short));
    unsigned short* node_xb = (unsigned short*)ws;  ws += align256((size_t)N * DIM * sizeof(unsigned short));
    unsigned short* exb = (unsigned short*)ws;      ws += align256((size_t)E * DIM * sizeof(unsigned short));
    unsigned short* xb  = (unsigned short*)ws;      ws += align256((size_t)N * DIM * sizeof(unsigned short));
    (void)ws_size;

    seg_offsets_kernel<<<cdiv(E + 1, 256), 256, 0, stream>>>(edge_seg, M, E, edge_off);
    seg_offsets_kernel<<<cdiv(N + 1, 256), 256, 0, stream>>>(node_seg, M, N, node_off);
    f32_to_bf16_kernel<<<cdiv(N * DIM / 4, 256), 256, 0, stream>>>(node_x, node_xb, N * DIM / 4);
    swizzle_w_kernel<<<32, 256, 0, stream>>>(W_e, W_n, wsw);

    const unsigned short* xcur = node_xb;
    for (int i = 0; i < L; ++i) {
        seg_mean_bf16_v2_kernel<<<cdiv(E, 16), 256, 0, stream>>>(
            (const uint4*)xcur, nodes_map, edge_off, (uint4*)exb, E);
        gemm_ln_relu_kernel<<<cdiv(E, ROWS_PER_BLOCK), 256, 0, stream>>>(
            exb, exb, wsw + (size_t)i * 16384, b_e + i * DIM, g_e + i * DIM, be_e + i * DIM, E);
        seg_mean_bf16_v2_kernel<<<cdiv(N, 16), 256, 0, stream>>>(
            (const uint4*)exb, edges_map, node_off, (uint4*)xb, N);
        gemm_ln_relu_kernel<<<cdiv(N, ROWS_PER_BLOCK), 256, 0, stream>>>(
            xb, xb, wsw + (size_t)(2 + i) * 16384, b_n + i * DIM, g_n + i * DIM, be_n + i * DIM, N);
        xcur = xb;
    }

    classifier_logsoftmax_v3_kernel<<<cdiv(N, 16 * CL_ROWS), 256, 0, stream>>>(
        (const uint4*)xcur, W_c, b_c, out, N);
}

// Round 8
// 381.982 us; speedup vs baseline: 4.6926x; 1.0667x over previous
//
#include <hip/hip_runtime.h>
#include <hip/hip_bf16.h>

#define DIM 128

typedef __bf16 bf16x8 __attribute__((ext_vector_type(8)));
typedef float f32x4 __attribute__((ext_vector_type(4)));

static inline int cdiv(int a, int b) { return (a + b - 1) / b; }
static inline size_t align256(size_t x) { return (x + 255) & ~size_t(255); }

__device__ inline unsigned short f2bf(float f) {
    union { float f; unsigned int u; } v; v.f = f;
    unsigned int r = v.u + 0x7fff + ((v.u >> 16) & 1);   // RNE
    return (unsigned short)(r >> 16);
}
__device__ inline float bf2f(unsigned short h) {
    union { unsigned int u; float f; } v; v.u = ((unsigned int)h) << 16;
    return v.f;
}

// -------- kernel 1: segment offsets via binary search (seg sorted ascending)
__global__ void seg_offsets_kernel(const int* __restrict__ seg, int m, int nseg,
                                   int* __restrict__ off) {
    int s = blockIdx.x * blockDim.x + threadIdx.x;
    if (s > nseg) return;
    int lo = 0, hi = m;
    while (lo < hi) {
        int mid = (lo + hi) >> 1;
        if (seg[mid] < s) lo = mid + 1; else hi = mid;
    }
    off[s] = lo;
}

// -------- kernel 2: fp32 -> bf16 convert (node_x), float4 granularity
__global__ void f32_to_bf16_kernel(const float* __restrict__ in,
                                   unsigned short* __restrict__ out, int n4) {
    int i = blockIdx.x * blockDim.x + threadIdx.x;
    if (i >= n4) return;
    float4 v = ((const float4*)in)[i];
    ushort4 o;
    o.x = f2bf(v.x); o.y = f2bf(v.y); o.z = f2bf(v.z); o.w = f2bf(v.w);
    ((ushort4*)out)[i] = o;
}

// -------- kernel 3: pre-swizzle W (4 matrices of 128x128 fp32) into frag-major bf16.
// Entry e=(t,n,lane): 8 bf16 = W[t*32 + (lane>>4)*8 + j][n*16 + (lane&15)], j=0..7.
__global__ void swizzle_w_kernel(const float* __restrict__ W_e, const float* __restrict__ W_n,
                                 unsigned short* __restrict__ wsw) {
    int gid = blockIdx.x * blockDim.x + threadIdx.x;  // 4 * 2048 threads
    int mi = gid >> 11;
    int e = gid & 2047;
    const float* W = (mi < 2) ? (W_e + (size_t)mi * DIM * DIM)
                              : (W_n + (size_t)(mi - 2) * DIM * DIM);
    int t = e >> 9, n = (e >> 6) & 7, lane = e & 63;
    int q = lane >> 4, c = lane & 15;
    int k0 = t * 32 + q * 8, col = n * 16 + c;
    unsigned short vals[8];
#pragma unroll
    for (int j = 0; j < 8; ++j) vals[j] = f2bf(W[(size_t)(k0 + j) * DIM + col]);
    ushort4* dst = (ushort4*)(wsw + (size_t)gid * 8);
    dst[0] = make_ushort4(vals[0], vals[1], vals[2], vals[3]);
    dst[1] = make_ushort4(vals[4], vals[5], vals[6], vals[7]);
}

// -------- kernel 4 v2: gather + segment mean, 4 segments per wave.
// Quarter-wave (16 lanes) per segment; lane reads a contiguous uint4 per member row.
__device__ inline void accum8(float* a, uint4 v, float wt) {
    unsigned int u[4] = {v.x, v.y, v.z, v.w};
#pragma unroll
    for (int i = 0; i < 4; ++i) {
        union { unsigned int ui; float f; } lo, hi;
        lo.ui = u[i] << 16;
        hi.ui = u[i] & 0xffff0000u;
        a[2 * i]     = fmaf(wt, lo.f, a[2 * i]);
        a[2 * i + 1] = fmaf(wt, hi.f, a[2 * i + 1]);
    }
}

__global__ __launch_bounds__(256)
void seg_mean_bf16_v2_kernel(const uint4* __restrict__ src, const int* __restrict__ map,
                             const int* __restrict__ off, uint4* __restrict__ dst,
                             int nseg) {
    int w = threadIdx.x >> 6, lane = threadIdx.x & 63;
    int g = lane >> 4, c16 = lane & 15;
    int s = blockIdx.x * 16 + w * 4 + g;
    int sc = min(s, nseg - 1);
    int beg = off[sc], end = off[sc + 1];

    float a[8] = {0.f, 0.f, 0.f, 0.f, 0.f, 0.f, 0.f, 0.f};

    for (int j = beg; j < end; j += 4) {
        int j1 = min(j + 1, end - 1), j2 = min(j + 2, end - 1), j3 = min(j + 3, end - 1);
        int r0 = map[j], r1 = map[j1], r2 = map[j2], r3 = map[j3];
        uint4 v0 = src[(size_t)r0 * 16 + c16];
        uint4 v1 = src[(size_t)r1 * 16 + c16];
        uint4 v2 = src[(size_t)r2 * 16 + c16];
        uint4 v3 = src[(size_t)r3 * 16 + c16];
        float w1 = (j + 1 < end) ? 1.f : 0.f;
        float w2 = (j + 2 < end) ? 1.f : 0.f;
        float w3 = (j + 3 < end) ? 1.f : 0.f;
        accum8(a, v0, 1.f);
        accum8(a, v1, w1);
        accum8(a, v2, w2);
        accum8(a, v3, w3);
    }

    if (s < nseg) {
        float inv = 1.f / fmaxf((float)(end - beg), 1.f);
        uint4 o;
        o.x = (unsigned int)f2bf(a[0] * inv) | ((unsigned int)f2bf(a[1] * inv) << 16);
        o.y = (unsigned int)f2bf(a[2] * inv) | ((unsigned int)f2bf(a[3] * inv) << 16);
        o.z = (unsigned int)f2bf(a[4] * inv) | ((unsigned int)f2bf(a[5] * inv) << 16);
        o.w = (unsigned int)f2bf(a[6] * inv) | ((unsigned int)f2bf(a[7] * inv) << 16);
        dst[(size_t)s * 16 + c16] = o;
    }
}

// -------- kernel 5 v2: Y = relu(LN(X @ W + b) * g + be), bf16 in/out, MFMA 16x16x32.
// One wave = 16 rows (RT=1), block = 64 rows. Bias pre-seeded in accumulator.
// Slim epilogue: ~5 VALU/elem, round-half-up bf16 cvt folded into store_d16_hi.
#define ROWS_PER_BLOCK 64

__global__ __launch_bounds__(256)
void gemm_ln_relu_v2_kernel(const unsigned short* __restrict__ X, unsigned short* __restrict__ Y,
                            const unsigned short* __restrict__ Wsw, const float* __restrict__ b,
                            const float* __restrict__ g, const float* __restrict__ be,
                            int nrows) {
    __shared__ bf16x8 wlds[2048];   // 32 KB, frag-major: [(t*8+n)*64 + lane]
    int tid = threadIdx.x;
    int w = tid >> 6, lane = tid & 63;
    int q = lane >> 4, c = lane & 15;

    {   // stage swizzled W (global layout == LDS layout)
        const uint4* gsrc = (const uint4*)Wsw;
        uint4* ldst = (uint4*)wlds;
#pragma unroll
        for (int i = 0; i < 8; ++i) ldst[tid + i * 256] = gsrc[tid + i * 256];
    }

    long tbase = (long)blockIdx.x * ROWS_PER_BLOCK + w * 16;

    // A fragments (4 x 16B), issued before the barrier to overlap staging latency.
    long rowA = tbase + c;
    if (rowA > nrows - 1) rowA = nrows - 1;   // clamp stays within this block's rows
    const bf16x8* ap = (const bf16x8*)(X + rowA * DIM + q * 8);
    bf16x8 a0 = ap[0], a1 = ap[4], a2 = ap[8], a3 = ap[12];

    float gcol[8], becol[8];
    f32x4 acc[8];
#pragma unroll
    for (int n = 0; n < 8; ++n) {
        int col = n * 16 + c;
        float bb = b[col];
        gcol[n] = g[col]; becol[n] = be[col];
        acc[n] = f32x4{bb, bb, bb, bb};       // bias seeded into MFMA C
    }

    __syncthreads();

#pragma unroll
    for (int n = 0; n < 8; ++n) {
        acc[n] = __builtin_amdgcn_mfma_f32_16x16x32_bf16(a0, wlds[(0 * 8 + n) * 64 + lane], acc[n], 0, 0, 0);
        acc[n] = __builtin_amdgcn_mfma_f32_16x16x32_bf16(a1, wlds[(1 * 8 + n) * 64 + lane], acc[n], 0, 0, 0);
        acc[n] = __builtin_amdgcn_mfma_f32_16x16x32_bf16(a2, wlds[(2 * 8 + n) * 64 + lane], acc[n], 0, 0, 0);
        acc[n] = __builtin_amdgcn_mfma_f32_16x16x32_bf16(a3, wlds[(3 * 8 + n) * 64 + lane], acc[n], 0, 0, 0);
    }

    // LN sums per row (lane's rows: tbase + q*4 + j, col n*16+c)
    float s1[4], s2[4];
#pragma unroll
    for (int j = 0; j < 4; ++j) {
        float t1 = 0.f, t2 = 0.f;
#pragma unroll
        for (int n = 0; n < 8; ++n) { float v = acc[n][j]; t1 += v; t2 = fmaf(v, v, t2); }
        s1[j] = t1; s2[j] = t2;
    }
#pragma unroll
    for (int o = 1; o < 16; o <<= 1)
#pragma unroll
        for (int j = 0; j < 4; ++j) {
            s1[j] += __shfl_xor(s1[j], o);
            s2[j] += __shfl_xor(s2[j], o);
        }

#pragma unroll
    for (int j = 0; j < 4; ++j) {
        long row = tbase + q * 4 + j;
        if (row >= nrows) continue;
        float m = s1[j] * (1.f / DIM);
        float var = fmaf(-m, m, s2[j] * (1.f / DIM));
        float inv = rsqrtf(var + 1e-5f);
        unsigned short* yp = Y + row * DIM + c;
#pragma unroll
        for (int n = 0; n < 8; ++n) {
            float d = acc[n][j] - m;
            float y = fmaxf(fmaf(d * inv, gcol[n], becol[n]), 0.f);
            unsigned int u = __builtin_bit_cast(unsigned int, y) + 0x8000u;  // half-up
            yp[n * 16] = (unsigned short)(u >> 16);   // -> global_store_short_d16_hi
        }
    }
}

// -------- kernel 6 v3: classifier + log_softmax, quarter-wave per row, 4 rows/quarter.
#define CL_ROWS 4
__global__ __launch_bounds__(256)
void classifier_logsoftmax_v3_kernel(const uint4* __restrict__ X,
                                     const float* __restrict__ Wc,
                                     const float* __restrict__ bc,
                                     float* __restrict__ out, int nrows) {
    int w = threadIdx.x >> 6, lane = threadIdx.x & 63;
    int g = lane >> 4, c16 = lane & 15;
    int r0 = (blockIdx.x * 16 + w * 4 + g) * CL_ROWS;
    if (r0 >= nrows) return;

    float wc[8][10];
#pragma unroll
    for (int j = 0; j < 8; ++j)
#pragma unroll
        for (int c = 0; c < 10; ++c) wc[j][c] = Wc[(c16 * 8 + j) * 10 + c];
    float bcv[10];
#pragma unroll
    for (int c = 0; c < 10; ++c) bcv[c] = bc[c];

    int rend = min(r0 + CL_ROWS, nrows);
    for (int r = r0; r < rend; ++r) {
        uint4 v = X[(size_t)r * 16 + c16];
        float x[8];
        {
            unsigned int u[4] = {v.x, v.y, v.z, v.w};
#pragma unroll
            for (int i = 0; i < 4; ++i) {
                union { unsigned int ui; float f; } lo, hi;
                lo.ui = u[i] << 16;
                hi.ui = u[i] & 0xffff0000u;
                x[2 * i] = lo.f; x[2 * i + 1] = hi.f;
            }
        }
        float acc[10];
#pragma unroll
        for (int c = 0; c < 10; ++c) acc[c] = 0.f;
#pragma unroll
        for (int j = 0; j < 8; ++j)
#pragma unroll
            for (int c = 0; c < 10; ++c) acc[c] = fmaf(x[j], wc[j][c], acc[c]);

#pragma unroll
        for (int o = 1; o < 16; o <<= 1)
#pragma unroll
            for (int c = 0; c < 10; ++c) acc[c] += __shfl_xor(acc[c], o);

#pragma unroll
        for (int c = 0; c < 10; ++c) acc[c] += bcv[c];

        float mx = acc[0];
#pragma unroll
        for (int c = 1; c < 10; ++c) mx = fmaxf(mx, acc[c]);
        float se = 0.f;
#pragma unroll
        for (int c = 0; c < 10; ++c) se += expf(acc[c] - mx);
        float lse = mx + logf(se);

        float myv = 0.f;
#pragma unroll
        for (int c = 0; c < 10; ++c) myv = (c16 == c) ? acc[c] : myv;
        if (c16 < 10) out[(size_t)r * 10 + c16] = myv - lse;
    }
}

extern "C" void kernel_launch(void* const* d_in, const int* in_sizes, int n_in,
                              void* d_out, int out_size, void* d_ws, size_t ws_size,
                              hipStream_t stream) {
    const float* node_x    = (const float*)d_in[0];
    const int*   nodes_map = (const int*)d_in[1];
    const int*   edge_seg  = (const int*)d_in[2];
    const int*   edges_map = (const int*)d_in[3];
    const int*   node_seg  = (const int*)d_in[4];
    const float* W_e = (const float*)d_in[6];
    const float* b_e = (const float*)d_in[7];
    const float* g_e = (const float*)d_in[8];
    const float* be_e= (const float*)d_in[9];
    const float* W_n = (const float*)d_in[10];
    const float* b_n = (const float*)d_in[11];
    const float* g_n = (const float*)d_in[12];
    const float* be_n= (const float*)d_in[13];
    const float* W_c = (const float*)d_in[14];
    const float* b_c = (const float*)d_in[15];
    float* out = (float*)d_out;

    const int N = in_sizes[0] / DIM;           // 100000
    const int M = in_sizes[1];                 // 800000
    const int E = 200000;                      // N_EDGES (problem constant)
    const int L = in_sizes[6] / (DIM * DIM);   // 2

    // workspace carve-up
    char* ws = (char*)d_ws;
    int* edge_off = (int*)ws;           ws += align256((size_t)(E + 1) * sizeof(int));
    int* node_off = (int*)ws;           ws += align256((size_t)(N + 1) * sizeof(int));
    unsigned short* wsw = (unsigned short*)ws;      ws += align256((size_t)4 * 2048 * 8 * sizeof(unsigned short));
    unsigned short* node_xb = (unsigned short*)ws;  ws += align256((size_t)N * DIM * sizeof(unsigned short));
    unsigned short* exb = (unsigned short*)ws;      ws += align256((size_t)E * DIM * sizeof(unsigned short));
    unsigned short* xb  = (unsigned short*)ws;      ws += align256((size_t)N * DIM * sizeof(unsigned short));
    (void)ws_size;

    seg_offsets_kernel<<<cdiv(E + 1, 256), 256, 0, stream>>>(edge_seg, M, E, edge_off);
    seg_offsets_kernel<<<cdiv(N + 1, 256), 256, 0, stream>>>(node_seg, M, N, node_off);
    f32_to_bf16_kernel<<<cdiv(N * DIM / 4, 256), 256, 0, stream>>>(node_x, node_xb, N * DIM / 4);
    swizzle_w_kernel<<<32, 256, 0, stream>>>(W_e, W_n, wsw);

    const unsigned short* xcur = node_xb;
    for (int i = 0; i < L; ++i) {
        seg_mean_bf16_v2_kernel<<<cdiv(E, 16), 256, 0, stream>>>(
            (const uint4*)xcur, nodes_map, edge_off, (uint4*)exb, E);
        gemm_ln_relu_v2_kernel<<<cdiv(E, ROWS_PER_BLOCK), 256, 0, stream>>>(
            exb, exb, wsw + (size_t)i * 16384, b_e + i * DIM, g_e + i * DIM, be_e + i * DIM, E);
        seg_mean_bf16_v2_kernel<<<cdiv(N, 16), 256, 0, stream>>>(
            (const uint4*)exb, edges_map, node_off, (uint4*)xb, N);
        gemm_ln_relu_v2_kernel<<<cdiv(N, ROWS_PER_BLOCK), 256, 0, stream>>>(
            xb, xb, wsw + (size_t)(2 + i) * 16384, b_n + i * DIM, g_n + i * DIM, be_n + i * DIM, N);
        xcur = xb;
    }

    classifier_logsoftmax_v3_kernel<<<cdiv(N, 16 * CL_ROWS), 256, 0, stream>>>(
        (const uint4*)xcur, W_c, b_c, out, N);
}

// Round 9
// 375.780 us; speedup vs baseline: 4.7701x; 1.0165x over previous
//
#include <hip/hip_runtime.h>
#include <hip/hip_bf16.h>

#define DIM 128

typedef __bf16 bf16x8 __attribute__((ext_vector_type(8)));
typedef float f32x4 __attribute__((ext_vector_type(4)));

static inline int cdiv(int a, int b) { return (a + b - 1) / b; }
static inline size_t align256(size_t x) { return (x + 255) & ~size_t(255); }

__device__ inline unsigned short f2bf(float f) {
    union { float f; unsigned int u; } v; v.f = f;
    unsigned int r = v.u + 0x7fff + ((v.u >> 16) & 1);   // RNE
    return (unsigned short)(r >> 16);
}
__device__ inline float bf2f(unsigned short h) {
    union { unsigned int u; float f; } v; v.u = ((unsigned int)h) << 16;
    return v.f;
}

// -------- kernel 1: segment offsets via binary search (seg sorted ascending)
__global__ void seg_offsets_kernel(const int* __restrict__ seg, int m, int nseg,
                                   int* __restrict__ off) {
    int s = blockIdx.x * blockDim.x + threadIdx.x;
    if (s > nseg) return;
    int lo = 0, hi = m;
    while (lo < hi) {
        int mid = (lo + hi) >> 1;
        if (seg[mid] < s) lo = mid + 1; else hi = mid;
    }
    off[s] = lo;
}

// -------- kernel 2: fp32 -> bf16 convert (node_x), float4 granularity
__global__ void f32_to_bf16_kernel(const float* __restrict__ in,
                                   unsigned short* __restrict__ out, int n4) {
    int i = blockIdx.x * blockDim.x + threadIdx.x;
    if (i >= n4) return;
    float4 v = ((const float4*)in)[i];
    ushort4 o;
    o.x = f2bf(v.x); o.y = f2bf(v.y); o.z = f2bf(v.z); o.w = f2bf(v.w);
    ((ushort4*)out)[i] = o;
}

// -------- kernel 3: pre-swizzle W (4 matrices of 128x128 fp32) into frag-major bf16.
// Entry e=(t,n,lane): 8 bf16 = W[t*32 + (lane>>4)*8 + j][n*16 + (lane&15)], j=0..7.
__global__ void swizzle_w_kernel(const float* __restrict__ W_e, const float* __restrict__ W_n,
                                 unsigned short* __restrict__ wsw) {
    int gid = blockIdx.x * blockDim.x + threadIdx.x;  // 4 * 2048 threads
    int mi = gid >> 11;
    int e = gid & 2047;
    const float* W = (mi < 2) ? (W_e + (size_t)mi * DIM * DIM)
                              : (W_n + (size_t)(mi - 2) * DIM * DIM);
    int t = e >> 9, n = (e >> 6) & 7, lane = e & 63;
    int q = lane >> 4, c = lane & 15;
    int k0 = t * 32 + q * 8, col = n * 16 + c;
    unsigned short vals[8];
#pragma unroll
    for (int j = 0; j < 8; ++j) vals[j] = f2bf(W[(size_t)(k0 + j) * DIM + col]);
    ushort4* dst = (ushort4*)(wsw + (size_t)gid * 8);
    dst[0] = make_ushort4(vals[0], vals[1], vals[2], vals[3]);
    dst[1] = make_ushort4(vals[4], vals[5], vals[6], vals[7]);
}

__device__ inline void accum8(float* a, uint4 v, float wt) {
    unsigned int u[4] = {v.x, v.y, v.z, v.w};
#pragma unroll
    for (int i = 0; i < 4; ++i) {
        union { unsigned int ui; float f; } lo, hi;
        lo.ui = u[i] << 16;
        hi.ui = u[i] & 0xffff0000u;
        a[2 * i]     = fmaf(wt, lo.f, a[2 * i]);
        a[2 * i + 1] = fmaf(wt, hi.f, a[2 * i + 1]);
    }
}

// -------- kernel 4: FUSED pool(seg-mean) + GEMM + LN + ReLU.
// Block = 64 segments. Phase 1: 16 quarter-waves pool 4 segments each into a
// 64x128 bf16 LDS tile (row stride 272 B -> max 2-way bank aliasing = free).
// Phase 2: per-wave 16-row MFMA 16x16x32 against W staged in LDS, bias seeded
// in accumulator, slim LN/ReLU epilogue, bf16 store (round-half-up cvt).
__global__ __launch_bounds__(256)
void fused_pool_gemm_ln_relu_kernel(const uint4* __restrict__ src,
                                    const int* __restrict__ map,
                                    const int* __restrict__ off,
                                    const unsigned short* __restrict__ Wsw,
                                    const float* __restrict__ b,
                                    const float* __restrict__ g,
                                    const float* __restrict__ be,
                                    unsigned short* __restrict__ Y,
                                    int nseg) {
    __shared__ bf16x8 wlds[2048];              // 32 KB, frag-major W
    __shared__ unsigned short alds[64][136];   // 17 KB pooled A-tile (pad 8 ushorts)
    int tid = threadIdx.x;
    int w = tid >> 6, lane = tid & 63;
    int q = lane >> 4, c = lane & 15;

    {   // stage swizzled W (global layout == LDS layout)
        const uint4* gsrc = (const uint4*)Wsw;
        uint4* ldst = (uint4*)wlds;
#pragma unroll
        for (int i = 0; i < 8; ++i) ldst[tid + i * 256] = gsrc[tid + i * 256];
    }

    int blockbase = blockIdx.x * 64;
    int qid = w * 4 + q;   // quarter id 0..15

    // ---- phase 1: pool 64 segments (quarter-wave per segment, 4 per quarter)
    for (int it = 0; it < 4; ++it) {
        int s_local = it * 16 + qid;
        int sc = min(blockbase + s_local, nseg - 1);
        int beg = off[sc], end = off[sc + 1];
        float a[8] = {0.f, 0.f, 0.f, 0.f, 0.f, 0.f, 0.f, 0.f};
        for (int j = beg; j < end; j += 4) {
            int j1 = min(j + 1, end - 1), j2 = min(j + 2, end - 1), j3 = min(j + 3, end - 1);
            int r0 = map[j], r1 = map[j1], r2 = map[j2], r3 = map[j3];
            uint4 v0 = src[(size_t)r0 * 16 + c];
            uint4 v1 = src[(size_t)r1 * 16 + c];
            uint4 v2 = src[(size_t)r2 * 16 + c];
            uint4 v3 = src[(size_t)r3 * 16 + c];
            accum8(a, v0, 1.f);
            accum8(a, v1, (j + 1 < end) ? 1.f : 0.f);
            accum8(a, v2, (j + 2 < end) ? 1.f : 0.f);
            accum8(a, v3, (j + 3 < end) ? 1.f : 0.f);
        }
        float inv = 1.f / fmaxf((float)(end - beg), 1.f);
        uint4 o;
        o.x = (unsigned int)f2bf(a[0] * inv) | ((unsigned int)f2bf(a[1] * inv) << 16);
        o.y = (unsigned int)f2bf(a[2] * inv) | ((unsigned int)f2bf(a[3] * inv) << 16);
        o.z = (unsigned int)f2bf(a[4] * inv) | ((unsigned int)f2bf(a[5] * inv) << 16);
        o.w = (unsigned int)f2bf(a[6] * inv) | ((unsigned int)f2bf(a[7] * inv) << 16);
        *(uint4*)&alds[s_local][c * 8] = o;
    }

    // epilogue params + bias-seeded accumulator (loads overlap phase-1 drain)
    float gcol[8], becol[8];
    f32x4 acc[8];
#pragma unroll
    for (int n = 0; n < 8; ++n) {
        int col = n * 16 + c;
        float bb = b[col];
        gcol[n] = g[col]; becol[n] = be[col];
        acc[n] = f32x4{bb, bb, bb, bb};
    }

    __syncthreads();

    // ---- phase 2: GEMM from LDS A-tile (wave w owns local rows w*16..w*16+15)
    const bf16x8* ap = (const bf16x8*)&alds[w * 16 + c][q * 8];
    bf16x8 a0 = ap[0], a1 = ap[4], a2 = ap[8], a3 = ap[12];

#pragma unroll
    for (int n = 0; n < 8; ++n) {
        acc[n] = __builtin_amdgcn_mfma_f32_16x16x32_bf16(a0, wlds[(0 * 8 + n) * 64 + lane], acc[n], 0, 0, 0);
        acc[n] = __builtin_amdgcn_mfma_f32_16x16x32_bf16(a1, wlds[(1 * 8 + n) * 64 + lane], acc[n], 0, 0, 0);
        acc[n] = __builtin_amdgcn_mfma_f32_16x16x32_bf16(a2, wlds[(2 * 8 + n) * 64 + lane], acc[n], 0, 0, 0);
        acc[n] = __builtin_amdgcn_mfma_f32_16x16x32_bf16(a3, wlds[(3 * 8 + n) * 64 + lane], acc[n], 0, 0, 0);
    }

    // LN sums per row (lane's rows: blockbase + w*16 + q*4 + j, col n*16+c)
    float s1[4], s2[4];
#pragma unroll
    for (int j = 0; j < 4; ++j) {
        float t1 = 0.f, t2 = 0.f;
#pragma unroll
        for (int n = 0; n < 8; ++n) { float v = acc[n][j]; t1 += v; t2 = fmaf(v, v, t2); }
        s1[j] = t1; s2[j] = t2;
    }
#pragma unroll
    for (int o = 1; o < 16; o <<= 1)
#pragma unroll
        for (int j = 0; j < 4; ++j) {
            s1[j] += __shfl_xor(s1[j], o);
            s2[j] += __shfl_xor(s2[j], o);
        }

#pragma unroll
    for (int j = 0; j < 4; ++j) {
        int row = blockbase + w * 16 + q * 4 + j;
        if (row >= nseg) continue;
        float m = s1[j] * (1.f / DIM);
        float var = fmaf(-m, m, s2[j] * (1.f / DIM));
        float inv = rsqrtf(var + 1e-5f);
        unsigned short* yp = Y + (size_t)row * DIM + c;
#pragma unroll
        for (int n = 0; n < 8; ++n) {
            float d = acc[n][j] - m;
            float y = fmaxf(fmaf(d * inv, gcol[n], becol[n]), 0.f);
            unsigned int u = __builtin_bit_cast(unsigned int, y) + 0x8000u;  // half-up
            yp[n * 16] = (unsigned short)(u >> 16);   // -> global_store_short_d16_hi
        }
    }
}

// -------- kernel 5: classifier + log_softmax, quarter-wave per row, 4 rows/quarter.
#define CL_ROWS 4
__global__ __launch_bounds__(256)
void classifier_logsoftmax_v3_kernel(const uint4* __restrict__ X,
                                     const float* __restrict__ Wc,
                                     const float* __restrict__ bc,
                                     float* __restrict__ out, int nrows) {
    int w = threadIdx.x >> 6, lane = threadIdx.x & 63;
    int g = lane >> 4, c16 = lane & 15;
    int r0 = (blockIdx.x * 16 + w * 4 + g) * CL_ROWS;
    if (r0 >= nrows) return;

    float wc[8][10];
#pragma unroll
    for (int j = 0; j < 8; ++j)
#pragma unroll
        for (int c = 0; c < 10; ++c) wc[j][c] = Wc[(c16 * 8 + j) * 10 + c];
    float bcv[10];
#pragma unroll
    for (int c = 0; c < 10; ++c) bcv[c] = bc[c];

    int rend = min(r0 + CL_ROWS, nrows);
    for (int r = r0; r < rend; ++r) {
        uint4 v = X[(size_t)r * 16 + c16];
        float x[8];
        {
            unsigned int u[4] = {v.x, v.y, v.z, v.w};
#pragma unroll
            for (int i = 0; i < 4; ++i) {
                union { unsigned int ui; float f; } lo, hi;
                lo.ui = u[i] << 16;
                hi.ui = u[i] & 0xffff0000u;
                x[2 * i] = lo.f; x[2 * i + 1] = hi.f;
            }
        }
        float acc[10];
#pragma unroll
        for (int c = 0; c < 10; ++c) acc[c] = 0.f;
#pragma unroll
        for (int j = 0; j < 8; ++j)
#pragma unroll
            for (int c = 0; c < 10; ++c) acc[c] = fmaf(x[j], wc[j][c], acc[c]);

#pragma unroll
        for (int o = 1; o < 16; o <<= 1)
#pragma unroll
            for (int c = 0; c < 10; ++c) acc[c] += __shfl_xor(acc[c], o);

#pragma unroll
        for (int c = 0; c < 10; ++c) acc[c] += bcv[c];

        float mx = acc[0];
#pragma unroll
        for (int c = 1; c < 10; ++c) mx = fmaxf(mx, acc[c]);
        float se = 0.f;
#pragma unroll
        for (int c = 0; c < 10; ++c) se += expf(acc[c] - mx);
        float lse = mx + logf(se);

        float myv = 0.f;
#pragma unroll
        for (int c = 0; c < 10; ++c) myv = (c16 == c) ? acc[c] : myv;
        if (c16 < 10) out[(size_t)r * 10 + c16] = myv - lse;
    }
}

extern "C" void kernel_launch(void* const* d_in, const int* in_sizes, int n_in,
                              void* d_out, int out_size, void* d_ws, size_t ws_size,
                              hipStream_t stream) {
    const float* node_x    = (const float*)d_in[0];
    const int*   nodes_map = (const int*)d_in[1];
    const int*   edge_seg  = (const int*)d_in[2];
    const int*   edges_map = (const int*)d_in[3];
    const int*   node_seg  = (const int*)d_in[4];
    const float* W_e = (const float*)d_in[6];
    const float* b_e = (const float*)d_in[7];
    const float* g_e = (const float*)d_in[8];
    const float* be_e= (const float*)d_in[9];
    const float* W_n = (const float*)d_in[10];
    const float* b_n = (const float*)d_in[11];
    const float* g_n = (const float*)d_in[12];
    const float* be_n= (const float*)d_in[13];
    const float* W_c = (const float*)d_in[14];
    const float* b_c = (const float*)d_in[15];
    float* out = (float*)d_out;

    const int N = in_sizes[0] / DIM;           // 100000
    const int M = in_sizes[1];                 // 800000
    const int E = 200000;                      // N_EDGES (problem constant)
    const int L = in_sizes[6] / (DIM * DIM);   // 2

    // workspace carve-up
    char* ws = (char*)d_ws;
    int* edge_off = (int*)ws;           ws += align256((size_t)(E + 1) * sizeof(int));
    int* node_off = (int*)ws;           ws += align256((size_t)(N + 1) * sizeof(int));
    unsigned short* wsw = (unsigned short*)ws;      ws += align256((size_t)4 * 2048 * 8 * sizeof(unsigned short));
    unsigned short* node_xb = (unsigned short*)ws;  ws += align256((size_t)N * DIM * sizeof(unsigned short));
    unsigned short* exb = (unsigned short*)ws;      ws += align256((size_t)E * DIM * sizeof(unsigned short));
    unsigned short* xb  = (unsigned short*)ws;      ws += align256((size_t)N * DIM * sizeof(unsigned short));
    (void)ws_size;

    seg_offsets_kernel<<<cdiv(E + 1, 256), 256, 0, stream>>>(edge_seg, M, E, edge_off);
    seg_offsets_kernel<<<cdiv(N + 1, 256), 256, 0, stream>>>(node_seg, M, N, node_off);
    f32_to_bf16_kernel<<<cdiv(N * DIM / 4, 256), 256, 0, stream>>>(node_x, node_xb, N * DIM / 4);
    swizzle_w_kernel<<<32, 256, 0, stream>>>(W_e, W_n, wsw);

    const unsigned short* xcur = node_xb;
    for (int i = 0; i < L; ++i) {
        // N2E: pool node rows per hyperedge, then edge-MLP
        fused_pool_gemm_ln_relu_kernel<<<cdiv(E, 64), 256, 0, stream>>>(
            (const uint4*)xcur, nodes_map, edge_off, wsw + (size_t)i * 16384,
            b_e + i * DIM, g_e + i * DIM, be_e + i * DIM, exb, E);
        // E2N: pool edge rows per node, then node-MLP
        fused_pool_gemm_ln_relu_kernel<<<cdiv(N, 64), 256, 0, stream>>>(
            (const uint4*)exb, edges_map, node_off, wsw + (size_t)(2 + i) * 16384,
            b_n + i * DIM, g_n + i * DIM, be_n + i * DIM, xb, N);
        xcur = xb;
    }

    classifier_logsoftmax_v3_kernel<<<cdiv(N, 16 * CL_ROWS), 256, 0, stream>>>(
        (const uint4*)xcur, W_c, b_c, out, N);
}

// Round 10
// 354.249 us; speedup vs baseline: 5.0600x; 1.0608x over previous
//
#include <hip/hip_runtime.h>
#include <hip/hip_bf16.h>

#define DIM 128

typedef __bf16 bf16x8 __attribute__((ext_vector_type(8)));
typedef float f32x4 __attribute__((ext_vector_type(4)));

static inline int cdiv(int a, int b) { return (a + b - 1) / b; }
static inline size_t align256(size_t x) { return (x + 255) & ~size_t(255); }

__device__ inline unsigned short f2bf(float f) {
    union { float f; unsigned int u; } v; v.f = f;
    unsigned int r = v.u + 0x7fff + ((v.u >> 16) & 1);   // RNE
    return (unsigned short)(r >> 16);
}
__device__ inline float bf2f(unsigned short h) {
    union { unsigned int u; float f; } v; v.u = ((unsigned int)h) << 16;
    return v.f;
}

// -------- kernel 1: segment offsets via binary search (seg sorted ascending)
__global__ void seg_offsets_kernel(const int* __restrict__ seg, int m, int nseg,
                                   int* __restrict__ off) {
    int s = blockIdx.x * blockDim.x + threadIdx.x;
    if (s > nseg) return;
    int lo = 0, hi = m;
    while (lo < hi) {
        int mid = (lo + hi) >> 1;
        if (seg[mid] < s) lo = mid + 1; else hi = mid;
    }
    off[s] = lo;
}

// -------- kernel 2: fp32 -> bf16 convert (node_x), float4 granularity
__global__ void f32_to_bf16_kernel(const float* __restrict__ in,
                                   unsigned short* __restrict__ out, int n4) {
    int i = blockIdx.x * blockDim.x + threadIdx.x;
    if (i >= n4) return;
    float4 v = ((const float4*)in)[i];
    ushort4 o;
    o.x = f2bf(v.x); o.y = f2bf(v.y); o.z = f2bf(v.z); o.w = f2bf(v.w);
    ((ushort4*)out)[i] = o;
}

// -------- kernel 3: pre-swizzle W (4 matrices of 128x128 fp32) into frag-major bf16.
// Entry e=(t,n,lane): 8 bf16 = W[t*32 + (lane>>4)*8 + j][n*16 + (lane&15)], j=0..7.
__global__ void swizzle_w_kernel(const float* __restrict__ W_e, const float* __restrict__ W_n,
                                 unsigned short* __restrict__ wsw) {
    int gid = blockIdx.x * blockDim.x + threadIdx.x;  // 4 * 2048 threads
    int mi = gid >> 11;
    int e = gid & 2047;
    const float* W = (mi < 2) ? (W_e + (size_t)mi * DIM * DIM)
                              : (W_n + (size_t)(mi - 2) * DIM * DIM);
    int t = e >> 9, n = (e >> 6) & 7, lane = e & 63;
    int q = lane >> 4, c = lane & 15;
    int k0 = t * 32 + q * 8, col = n * 16 + c;
    unsigned short vals[8];
#pragma unroll
    for (int j = 0; j < 8; ++j) vals[j] = f2bf(W[(size_t)(k0 + j) * DIM + col]);
    ushort4* dst = (ushort4*)(wsw + (size_t)gid * 8);
    dst[0] = make_ushort4(vals[0], vals[1], vals[2], vals[3]);
    dst[1] = make_ushort4(vals[4], vals[5], vals[6], vals[7]);
}

__device__ inline void accum8(float* a, uint4 v, float wt) {
    unsigned int u[4] = {v.x, v.y, v.z, v.w};
#pragma unroll
    for (int i = 0; i < 4; ++i) {
        union { unsigned int ui; float f; } lo, hi;
        lo.ui = u[i] << 16;
        hi.ui = u[i] & 0xffff0000u;
        a[2 * i]     = fmaf(wt, lo.f, a[2 * i]);
        a[2 * i + 1] = fmaf(wt, hi.f, a[2 * i + 1]);
    }
}

// -------- kernel 4 v2: FUSED pool + GEMM + LN + ReLU, wave-decoupled.
// 512 threads = 8 waves; block = 128 segments; wave w owns segments w*16..w*16+15:
// it pools them (quarter-wave per segment) into an XOR-swizzled LDS tile and MFMAs
// those same rows — no barrier between pool and GEMM (wave-local ds ordering).
// Single __syncthreads() after W staging. LDS = 32KB W + 32KB A = 64KB, 2 blocks/CU.
__global__ __launch_bounds__(512)
void fused_pool_gemm_ln_relu_v2_kernel(const uint4* __restrict__ src,
                                       const int* __restrict__ map,
                                       const int* __restrict__ off,
                                       const unsigned short* __restrict__ Wsw,
                                       const float* __restrict__ b,
                                       const float* __restrict__ g,
                                       const float* __restrict__ be,
                                       unsigned short* __restrict__ Y,
                                       int nseg) {
    __shared__ bf16x8 wlds[2048];            // 32 KB, frag-major W
    __shared__ unsigned short alds[128 * 128]; // 32 KB pooled A-tile, XOR-swizzled
    int tid = threadIdx.x;
    int w = tid >> 6, lane = tid & 63;
    int q = lane >> 4, c = lane & 15;

    {   // stage swizzled W (global layout == LDS layout)
        const uint4* gsrc = (const uint4*)Wsw;
        uint4* ldst = (uint4*)wlds;
#pragma unroll
        for (int i = 0; i < 4; ++i) ldst[tid + i * 512] = gsrc[tid + i * 512];
    }

    int blockbase = blockIdx.x * 128;
    int wavebase = w * 16;

    // epilogue params + bias-seeded accumulator (issued early, latency hidden)
    float gcol[8], becol[8];
    f32x4 acc[8];
#pragma unroll
    for (int n = 0; n < 8; ++n) {
        int col = n * 16 + c;
        float bb = b[col];
        gcol[n] = g[col]; becol[n] = be[col];
        acc[n] = f32x4{bb, bb, bb, bb};
    }

    __syncthreads();   // only barrier: W visible to all waves

    // ---- phase 1: wave pools its own 16 rows (quarter per segment, 4 each)
    for (int it = 0; it < 4; ++it) {
        int s_local = wavebase + it * 4 + q;
        int sc = min(blockbase + s_local, nseg - 1);
        int beg = off[sc], end = off[sc + 1];
        float a[8] = {0.f, 0.f, 0.f, 0.f, 0.f, 0.f, 0.f, 0.f};
        for (int j = beg; j < end; j += 4) {
            int j1 = min(j + 1, end - 1), j2 = min(j + 2, end - 1), j3 = min(j + 3, end - 1);
            int r0 = map[j], r1 = map[j1], r2 = map[j2], r3 = map[j3];
            uint4 v0 = src[(size_t)r0 * 16 + c];
            uint4 v1 = src[(size_t)r1 * 16 + c];
            uint4 v2 = src[(size_t)r2 * 16 + c];
            uint4 v3 = src[(size_t)r3 * 16 + c];
            accum8(a, v0, 1.f);
            accum8(a, v1, (j + 1 < end) ? 1.f : 0.f);
            accum8(a, v2, (j + 2 < end) ? 1.f : 0.f);
            accum8(a, v3, (j + 3 < end) ? 1.f : 0.f);
        }
        float inv = 1.f / fmaxf((float)(end - beg), 1.f);
        uint4 o;
        o.x = (unsigned int)f2bf(a[0] * inv) | ((unsigned int)f2bf(a[1] * inv) << 16);
        o.y = (unsigned int)f2bf(a[2] * inv) | ((unsigned int)f2bf(a[3] * inv) << 16);
        o.z = (unsigned int)f2bf(a[4] * inv) | ((unsigned int)f2bf(a[5] * inv) << 16);
        o.w = (unsigned int)f2bf(a[6] * inv) | ((unsigned int)f2bf(a[7] * inv) << 16);
        // XOR-swizzled store: row s_local, logical chunk c -> physical c ^ (row&7)
        uint4* wrow = (uint4*)(alds + (size_t)s_local * 128);
        wrow[c ^ (s_local & 7)] = o;
    }

    // ---- phase 2: GEMM from own LDS rows (ds ordering is wave-local; no barrier)
    const uint4* arow = (const uint4*)(alds + (size_t)(wavebase + c) * 128);
    int key = c & 7;   // (wavebase+c)&7 == c&7
    bf16x8 a0 = *(const bf16x8*)&arow[(q + 0) ^ key];
    bf16x8 a1 = *(const bf16x8*)&arow[(q + 4) ^ key];
    bf16x8 a2 = *(const bf16x8*)&arow[(q + 8) ^ key];
    bf16x8 a3 = *(const bf16x8*)&arow[(q + 12) ^ key];

#pragma unroll
    for (int n = 0; n < 8; ++n) {
        acc[n] = __builtin_amdgcn_mfma_f32_16x16x32_bf16(a0, wlds[(0 * 8 + n) * 64 + lane], acc[n], 0, 0, 0);
        acc[n] = __builtin_amdgcn_mfma_f32_16x16x32_bf16(a1, wlds[(1 * 8 + n) * 64 + lane], acc[n], 0, 0, 0);
        acc[n] = __builtin_amdgcn_mfma_f32_16x16x32_bf16(a2, wlds[(2 * 8 + n) * 64 + lane], acc[n], 0, 0, 0);
        acc[n] = __builtin_amdgcn_mfma_f32_16x16x32_bf16(a3, wlds[(3 * 8 + n) * 64 + lane], acc[n], 0, 0, 0);
    }

    // LN sums per row (lane's rows: blockbase + wavebase + q*4 + j, col n*16+c)
    float s1[4], s2[4];
#pragma unroll
    for (int j = 0; j < 4; ++j) {
        float t1 = 0.f, t2 = 0.f;
#pragma unroll
        for (int n = 0; n < 8; ++n) { float v = acc[n][j]; t1 += v; t2 = fmaf(v, v, t2); }
        s1[j] = t1; s2[j] = t2;
    }
#pragma unroll
    for (int o = 1; o < 16; o <<= 1)
#pragma unroll
        for (int j = 0; j < 4; ++j) {
            s1[j] += __shfl_xor(s1[j], o);
            s2[j] += __shfl_xor(s2[j], o);
        }

#pragma unroll
    for (int j = 0; j < 4; ++j) {
        int row = blockbase + wavebase + q * 4 + j;
        if (row >= nseg) continue;
        float m = s1[j] * (1.f / DIM);
        float var = fmaf(-m, m, s2[j] * (1.f / DIM));
        float inv = rsqrtf(var + 1e-5f);
        unsigned short* yp = Y + (size_t)row * DIM + c;
#pragma unroll
        for (int n = 0; n < 8; ++n) {
            float d = acc[n][j] - m;
            float y = fmaxf(fmaf(d * inv, gcol[n], becol[n]), 0.f);
            unsigned int u = __builtin_bit_cast(unsigned int, y) + 0x8000u;  // half-up
            yp[n * 16] = (unsigned short)(u >> 16);   // -> global_store_short_d16_hi
        }
    }
}

// -------- kernel 5: classifier + log_softmax, quarter-wave per row, 4 rows/quarter.
#define CL_ROWS 4
__global__ __launch_bounds__(256)
void classifier_logsoftmax_v3_kernel(const uint4* __restrict__ X,
                                     const float* __restrict__ Wc,
                                     const float* __restrict__ bc,
                                     float* __restrict__ out, int nrows) {
    int w = threadIdx.x >> 6, lane = threadIdx.x & 63;
    int g = lane >> 4, c16 = lane & 15;
    int r0 = (blockIdx.x * 16 + w * 4 + g) * CL_ROWS;
    if (r0 >= nrows) return;

    float wc[8][10];
#pragma unroll
    for (int j = 0; j < 8; ++j)
#pragma unroll
        for (int c = 0; c < 10; ++c) wc[j][c] = Wc[(c16 * 8 + j) * 10 + c];
    float bcv[10];
#pragma unroll
    for (int c = 0; c < 10; ++c) bcv[c] = bc[c];

    int rend = min(r0 + CL_ROWS, nrows);
    for (int r = r0; r < rend; ++r) {
        uint4 v = X[(size_t)r * 16 + c16];
        float x[8];
        {
            unsigned int u[4] = {v.x, v.y, v.z, v.w};
#pragma unroll
            for (int i = 0; i < 4; ++i) {
                union { unsigned int ui; float f; } lo, hi;
                lo.ui = u[i] << 16;
                hi.ui = u[i] & 0xffff0000u;
                x[2 * i] = lo.f; x[2 * i + 1] = hi.f;
            }
        }
        float acc[10];
#pragma unroll
        for (int c = 0; c < 10; ++c) acc[c] = 0.f;
#pragma unroll
        for (int j = 0; j < 8; ++j)
#pragma unroll
            for (int c = 0; c < 10; ++c) acc[c] = fmaf(x[j], wc[j][c], acc[c]);

#pragma unroll
        for (int o = 1; o < 16; o <<= 1)
#pragma unroll
            for (int c = 0; c < 10; ++c) acc[c] += __shfl_xor(acc[c], o);

#pragma unroll
        for (int c = 0; c < 10; ++c) acc[c] += bcv[c];

        float mx = acc[0];
#pragma unroll
        for (int c = 1; c < 10; ++c) mx = fmaxf(mx, acc[c]);
        float se = 0.f;
#pragma unroll
        for (int c = 0; c < 10; ++c) se += expf(acc[c] - mx);
        float lse = mx + logf(se);

        float myv = 0.f;
#pragma unroll
        for (int c = 0; c < 10; ++c) myv = (c16 == c) ? acc[c] : myv;
        if (c16 < 10) out[(size_t)r * 10 + c16] = myv - lse;
    }
}

extern "C" void kernel_launch(void* const* d_in, const int* in_sizes, int n_in,
                              void* d_out, int out_size, void* d_ws, size_t ws_size,
                              hipStream_t stream) {
    const float* node_x    = (const float*)d_in[0];
    const int*   nodes_map = (const int*)d_in[1];
    const int*   edge_seg  = (const int*)d_in[2];
    const int*   edges_map = (const int*)d_in[3];
    const int*   node_seg  = (const int*)d_in[4];
    const float* W_e = (const float*)d_in[6];
    const float* b_e = (const float*)d_in[7];
    const float* g_e = (const float*)d_in[8];
    const float* be_e= (const float*)d_in[9];
    const float* W_n = (const float*)d_in[10];
    const float* b_n = (const float*)d_in[11];
    const float* g_n = (const float*)d_in[12];
    const float* be_n= (const float*)d_in[13];
    const float* W_c = (const float*)d_in[14];
    const float* b_c = (const float*)d_in[15];
    float* out = (float*)d_out;

    const int N = in_sizes[0] / DIM;           // 100000
    const int M = in_sizes[1];                 // 800000
    const int E = 200000;                      // N_EDGES (problem constant)
    const int L = in_sizes[6] / (DIM * DIM);   // 2

    // workspace carve-up
    char* ws = (char*)d_ws;
    int* edge_off = (int*)ws;           ws += align256((size_t)(E + 1) * sizeof(int));
    int* node_off = (int*)ws;           ws += align256((size_t)(N + 1) * sizeof(int));
    unsigned short* wsw = (unsigned short*)ws;      ws += align256((size_t)4 * 2048 * 8 * sizeof(unsigned short));
    unsigned short* node_xb = (unsigned short*)ws;  ws += align256((size_t)N * DIM * sizeof(unsigned short));
    unsigned short* exb = (unsigned short*)ws;      ws += align256((size_t)E * DIM * sizeof(unsigned short));
    unsigned short* xb  = (unsigned short*)ws;      ws += align256((size_t)N * DIM * sizeof(unsigned short));
    (void)ws_size;

    seg_offsets_kernel<<<cdiv(E + 1, 256), 256, 0, stream>>>(edge_seg, M, E, edge_off);
    seg_offsets_kernel<<<cdiv(N + 1, 256), 256, 0, stream>>>(node_seg, M, N, node_off);
    f32_to_bf16_kernel<<<cdiv(N * DIM / 4, 256), 256, 0, stream>>>(node_x, node_xb, N * DIM / 4);
    swizzle_w_kernel<<<32, 256, 0, stream>>>(W_e, W_n, wsw);

    const unsigned short* xcur = node_xb;
    for (int i = 0; i < L; ++i) {
        // N2E: pool node rows per hyperedge, then edge-MLP
        fused_pool_gemm_ln_relu_v2_kernel<<<cdiv(E, 128), 512, 0, stream>>>(
            (const uint4*)xcur, nodes_map, edge_off, wsw + (size_t)i * 16384,
            b_e + i * DIM, g_e + i * DIM, be_e + i * DIM, exb, E);
        // E2N: pool edge rows per node, then node-MLP
        fused_pool_gemm_ln_relu_v2_kernel<<<cdiv(N, 128), 512, 0, stream>>>(
            (const uint4*)exb, edges_map, node_off, wsw + (size_t)(2 + i) * 16384,
            b_n + i * DIM, g_n + i * DIM, be_n + i * DIM, xb, N);
        xcur = xb;
    }

    classifier_logsoftmax_v3_kernel<<<cdiv(N, 16 * CL_ROWS), 256, 0, stream>>>(
        (const uint4*)xcur, W_c, b_c, out, N);
}